// Round 18
// baseline (372.962 us; speedup 1.0000x reference)
//
#include <hip/hip_runtime.h>
#include <hip/hip_bf16.h>
#include <math.h>

#define THREADS 256
typedef _Float16 h16;

__device__ __forceinline__ void ld8h(const h16* p, float* f) {
    union { uint4 u; h16 h[8]; } c;
    c.u = *(const uint4*)p;
#pragma unroll
    for (int j = 0; j < 8; ++j) f[j] = (float)c.h[j];
}

// ---------------------------------------------------------------------------
// XCD-partitioned histogram (atomics stay L2-local per dst range), int4 scan
// ---------------------------------------------------------------------------
__global__ __launch_bounds__(256) void count_part_kernel(
    const int* __restrict__ dst, int* __restrict__ cnt, int E, int n)
{
    const int cls = blockIdx.x & 7;
    const int nb  = gridDim.x >> 3;
    const int sub = blockIdx.x >> 3;
    const int lo = (int)((long long)n * cls / 8);
    const int hi = (int)((long long)n * (cls + 1) / 8);
    const int stride = nb * 256;
    const int E4 = E >> 2;
    for (int t = sub * 256 + threadIdx.x; t < E4; t += stride) {
        int4 d = ((const int4*)dst)[t];
        if (d.x >= lo && d.x < hi) atomicAdd(&cnt[d.x], 1);
        if (d.y >= lo && d.y < hi) atomicAdd(&cnt[d.y], 1);
        if (d.z >= lo && d.z < hi) atomicAdd(&cnt[d.z], 1);
        if (d.w >= lo && d.w < hi) atomicAdd(&cnt[d.w], 1);
    }
    for (int e = (E4 << 2) + sub * 256 + threadIdx.x; e < E; e += stride) {
        int d = dst[e];
        if (d >= lo && d < hi) atomicAdd(&cnt[d], 1);
    }
}

// ---------------------------------------------------------------------------
// scan_p1 (blocks [0,NB)) + weight collapse:
//   block NB: chain C~_m = W_{m+1}@C~_{m+1} (C~_10 = Wfmid), beta'_m = b_m@C~_m,
//             then betaf1' = (b1@W2)@Wf1, b2' = b2@Wf1
//   blocks NB+1..NB+15: T = W2@Wf1 (3840 elems, parallel)
// ---------------------------------------------------------------------------
__global__ __launch_bounds__(256) void scanp1_pre_kernel(
    const int* __restrict__ cnt, int* __restrict__ partial, int n, int NB,
    const float* __restrict__ Wl, const float* __restrict__ bl,
    const float* __restrict__ W2, const float* __restrict__ b1,
    const float* __restrict__ b2, const float* __restrict__ Wf,
    float* __restrict__ CM, float* __restrict__ betas,
    float* __restrict__ T, float* __restrict__ betaf1p, float* __restrict__ b2p)
{
    __shared__ __align__(16) float smem[5200];   // 20.8 KB (chain needs most)
    const int tid = threadIdx.x;
    const int bid = blockIdx.x;

    if (bid < NB) {
        int* red = (int*)smem;
        int base = bid * 1024 + tid * 4;
        int s = 0;
        if (base + 3 < n) {
            int4 v = *(const int4*)(cnt + base);
            s = v.x + v.y + v.z + v.w;
        } else {
            for (int k = 0; k < 4; k++) { int i = base + k; if (i < n) s += cnt[i]; }
        }
        red[tid] = s;
        __syncthreads();
        for (int off = 128; off > 0; off >>= 1) {
            if (tid < off) red[tid] += red[tid + off];
            __syncthreads();
        }
        if (tid == 0) partial[bid] = red[0];
        return;
    }

    if (bid == NB) {
        // ---- chain block ----
        float* Ca  = smem;            // 1600
        float* Cb  = smem + 1600;     // 1600
        float* sWm = smem + 3200;     // 1600
        float* bls = smem + 4800;     // 400
        for (int idx = tid; idx < 100; idx += 256)
            ((float4*)bls)[idx] = ((const float4*)bl)[idx];
        for (int idx = tid; idx < 400; idx += 256)
            ((float4*)Ca)[idx] = ((const float4*)(Wf + 3840))[idx];   // C~_10 = Wfmid
        __syncthreads();
        if (tid < 40) {   // beta'_10 = b_10 @ Wfmid
            float s = 0.f;
#pragma unroll
            for (int k = 0; k < 40; ++k) s = fmaf(bls[360 + k], Ca[k * 40 + tid], s);
            betas[360 + tid] = s;
        }
        __syncthreads();
        float* cur = Ca;
        float* nxt = Cb;
        for (int m = 9; m >= 0; --m) {
            for (int idx = tid; idx < 400; idx += 256)
                ((float4*)sWm)[idx] = ((const float4*)(Wl + (size_t)m * 1600))[idx];
            __syncthreads();
            for (int sid = tid; sid < 400; sid += 256) {
                int i = sid / 10, jq = sid - (sid / 10) * 10;
                const float4* wr4 = (const float4*)&sWm[i * 40];
                const float4* c4 = (const float4*)cur;
                float4 a = make_float4(0.f, 0.f, 0.f, 0.f);
#pragma unroll
                for (int k4 = 0; k4 < 10; ++k4) {
                    float4 w = wr4[k4];
                    float4 c0 = c4[(k4 * 4 + 0) * 10 + jq];
                    float4 c1 = c4[(k4 * 4 + 1) * 10 + jq];
                    float4 c2 = c4[(k4 * 4 + 2) * 10 + jq];
                    float4 c3 = c4[(k4 * 4 + 3) * 10 + jq];
                    a.x = fmaf(w.x, c0.x, fmaf(w.y, c1.x, fmaf(w.z, c2.x, fmaf(w.w, c3.x, a.x))));
                    a.y = fmaf(w.x, c0.y, fmaf(w.y, c1.y, fmaf(w.z, c2.y, fmaf(w.w, c3.y, a.y))));
                    a.z = fmaf(w.x, c0.z, fmaf(w.y, c1.z, fmaf(w.z, c2.z, fmaf(w.w, c3.z, a.z))));
                    a.w = fmaf(w.x, c0.w, fmaf(w.y, c1.w, fmaf(w.z, c2.w, fmaf(w.w, c3.w, a.w))));
                }
                ((float4*)nxt)[sid] = a;
            }
            __syncthreads();
            if (m >= 1 && tid < 40) {
                float s = 0.f;
                const float* br = &bls[(m - 1) * 40];
#pragma unroll
                for (int k = 0; k < 40; ++k) s = fmaf(br[k], nxt[k * 40 + tid], s);
                betas[(size_t)(m - 1) * 40 + tid] = s;
            }
            float* t = cur; cur = nxt; nxt = t;
            __syncthreads();
        }
        for (int idx = tid; idx < 1600; idx += 256) CM[idx] = cur[idx];
        __syncthreads();

        // ---- betaf1' / b2' (Wf1 re-staged into freed smem) ----
        float* sWf1 = smem;           // 3840
        float* vq   = smem + 3840;    // 96
        for (int q2 = tid; q2 < 960; q2 += 256)
            ((float4*)sWf1)[q2] = ((const float4*)Wf)[q2];
        if (tid < 96) {               // vq = b1 @ W2 (global reads, coalesced)
            float s = 0.f;
            for (int k = 0; k < 96; ++k) s = fmaf(b1[k], W2[(size_t)k * 96 + tid], s);
            vq[tid] = s;
        }
        __syncthreads();
        if (tid < 40) {
            float s1 = 0.f, s2 = 0.f;
            for (int q = 0; q < 96; ++q) {
                float w = sWf1[q * 40 + tid];
                s1 = fmaf(vq[q], w, s1);
                s2 = fmaf(b2[q], w, s2);
            }
            betaf1p[tid] = s1;
            b2p[tid] = s2;
        }
        return;
    }

    // ---- T blocks: T[k][j] = sum_q W2[k][q] * Wf1[q][j] ----
    {
        int tb = bid - NB - 1;            // 0..14
        int idx = tb * 256 + tid;         // < 3840
        float* sWf1 = smem;
        for (int q2 = tid; q2 < 960; q2 += 256)
            ((float4*)sWf1)[q2] = ((const float4*)Wf)[q2];
        __syncthreads();
        int k = idx / 40, j = idx - (idx / 40) * 40;
        float s = 0.f;
#pragma unroll 8
        for (int q = 0; q < 96; ++q) s = fmaf(W2[(size_t)k * 96 + q], sWf1[q * 40 + j], s);
        T[idx] = s;
    }
}

// ---------------------------------------------------------------------------
// GEMM body: Y = (X @ W) [* dinv[i] if DODINV], TO out (pointer-passed smem)
// ---------------------------------------------------------------------------
template<int FIN, int FOUT, typename TX, typename TO, int DODINV>
__device__ __forceinline__ void gemm_body(
    const TX* __restrict__ X, const float* __restrict__ W,
    const float* __restrict__ dinv, TO* __restrict__ Y, int n,
    float* sX, float* sW, int bid, int tid)
{
    constexpr int KC = (FIN % 32 == 0) ? 32 : FIN;
    constexpr int NCHUNK = FIN / KC;
    constexpr int TN = (FOUT + 15) / 16;
    constexpr int BM = 64;
    constexpr int KP = KC + 4;

    const int tj = tid & 15;
    const int ti = tid >> 4;
    const int i0 = bid * BM;

    float acc[4][TN] = {};

    for (int c = 0; c < NCHUNK; ++c) {
        const int k0 = c * KC;
        __syncthreads();
        if constexpr (sizeof(TX) == 2) {
            constexpr int K8 = KC / 8;
            for (int v = tid; v < BM * K8; v += 256) {
                int r = v / K8, q = v - r * K8;
                int gi = i0 + r;
                float f[8] = {0.f, 0.f, 0.f, 0.f, 0.f, 0.f, 0.f, 0.f};
                if (gi < n) ld8h((const h16*)X + (size_t)gi * FIN + k0 + q * 8, f);
                float* p = &sX[r * KP + q * 8];
#pragma unroll
                for (int j = 0; j < 8; ++j) p[j] = f[j];
            }
        } else {
            constexpr int K4 = KC / 4;
            for (int v = tid; v < BM * K4; v += 256) {
                int r = v / K4, q = v - r * K4;
                int gi = i0 + r;
                float4 val = (gi < n) ? *(const float4*)((const float*)X + (size_t)gi * FIN + k0 + q * 4)
                                      : make_float4(0.f, 0.f, 0.f, 0.f);
                float* p = &sX[r * KP + q * 4];
                p[0] = val.x; p[1] = val.y; p[2] = val.z; p[3] = val.w;
            }
        }
        for (int v = tid; v < KC * FOUT; v += 256) {
            int kk = v / FOUT;
            int j = v - kk * FOUT;
            sW[j * KP + kk] = W[(size_t)(k0 + kk) * FOUT + j];
        }
        __syncthreads();
#pragma unroll
        for (int kk = 0; kk < KC; kk += 4) {
            float4 xv[4];
#pragma unroll
            for (int m = 0; m < 4; ++m)
                xv[m] = *(const float4*)&sX[(ti + 16 * m) * KP + kk];
#pragma unroll
            for (int u = 0; u < TN; ++u) {
                float4 wv = *(const float4*)&sW[(tj + 16 * u) * KP + kk];
#pragma unroll
                for (int m = 0; m < 4; ++m) {
                    acc[m][u] = fmaf(xv[m].x, wv.x, acc[m][u]);
                    acc[m][u] = fmaf(xv[m].y, wv.y, acc[m][u]);
                    acc[m][u] = fmaf(xv[m].z, wv.z, acc[m][u]);
                    acc[m][u] = fmaf(xv[m].w, wv.w, acc[m][u]);
                }
            }
        }
    }

#pragma unroll
    for (int m = 0; m < 4; ++m) {
        int gi = i0 + ti + 16 * m;
        if (gi >= n) continue;
        float dv = 1.f;
        if constexpr (DODINV) dv = dinv[gi];
#pragma unroll
        for (int u = 0; u < TN; ++u) {
            int j = tj + 16 * u;
            if (j < FOUT) Y[(size_t)gi * FOUT + j] = (TO)(acc[m][u] * dv);
        }
    }
}

// ---------------------------------------------------------------------------
// Merged: scatter (blocks [0,PB)) + gemm y@CM->Z0 (next gb) + gemm x@WF->F0.
// Scatter body: 4 VGPR / 0 LDS, so union footprint == small-GEMM footprint
// (TN=3, ~80 VGPR, 19.7 KB LDS -> >=6 blocks/CU; scatter residency preserved).
// ---------------------------------------------------------------------------
__global__ __launch_bounds__(256) void scatter_gemms_kernel(
    const int* __restrict__ src, const int* __restrict__ dst,
    int* __restrict__ cursor, int* __restrict__ col, int E, int n, int PB, int gb,
    const float* __restrict__ y, const float* __restrict__ CM, h16* __restrict__ Z0,
    const float* __restrict__ x, const float* __restrict__ WF, h16* __restrict__ F0,
    const float* __restrict__ dinv)
{
    __shared__ __align__(16) float smem[4928];   // 19.7 KB (gemm<40,40>)
    const int tid = threadIdx.x;
    int bid = blockIdx.x;
    if (bid < PB) {
        const int cls = bid & 7;
        const int nb  = PB >> 3;
        const int sub = bid >> 3;
        const int lo = (int)((long long)n * cls / 8);
        const int hi = (int)((long long)n * (cls + 1) / 8);
        const int stride = nb * 256;
        const int E4 = E >> 2;
        for (int t = sub * 256 + tid; t < E4; t += stride) {
            int4 d = ((const int4*)dst)[t];
            int4 s = ((const int4*)src)[t];
            if (d.x >= lo && d.x < hi) { int p = atomicAdd(&cursor[d.x], 1); col[p] = s.x; }
            if (d.y >= lo && d.y < hi) { int p = atomicAdd(&cursor[d.y], 1); col[p] = s.y; }
            if (d.z >= lo && d.z < hi) { int p = atomicAdd(&cursor[d.z], 1); col[p] = s.z; }
            if (d.w >= lo && d.w < hi) { int p = atomicAdd(&cursor[d.w], 1); col[p] = s.w; }
        }
        for (int e = (E4 << 2) + sub * 256 + tid; e < E; e += stride) {
            int d = dst[e];
            if (d >= lo && d < hi) { int p = atomicAdd(&cursor[d], 1); col[p] = src[e]; }
        }
        return;
    }
    bid -= PB;
    if (bid < gb) {
        gemm_body<40, 40, float, h16, 1>(y, CM, dinv, Z0, n, smem, smem + 64 * 44, bid, tid);
        return;
    }
    bid -= gb;
    gemm_body<128, 40, float, h16, 1>(x, WF, dinv, F0, n, smem, smem + 64 * 36, bid, tid);
}

// ---------------------------------------------------------------------------
// scan_p2 (block 0) + WF = W1@T (blocks 1..20) + DW40 = dwe@Wfbot (blocks 21..)
// ---------------------------------------------------------------------------
__global__ __launch_bounds__(256) void scanp2_wf_dw_kernel(
    int* __restrict__ partial, int* __restrict__ rowptr, int nb, int n,
    const float* __restrict__ W1, const float* __restrict__ T, float* __restrict__ WF,
    const float* __restrict__ dwe, const float* __restrict__ Wfbot, float* __restrict__ DW40)
{
    __shared__ __align__(16) float smem[4032];   // 16.1 KB (gemm<64,40> needs most)
    const int tid = threadIdx.x;
    const int bid = blockIdx.x;
    if (bid == 0) {
        int* sm = (int*)smem;
        int v = (tid < nb) ? partial[tid] : 0;
        sm[tid] = v;
        __syncthreads();
        int acc = v;
        for (int off = 1; off < 256; off <<= 1) {
            int t = (tid >= off) ? sm[tid - off] : 0;
            __syncthreads();
            acc += t;
            sm[tid] = acc;
            __syncthreads();
        }
        if (tid < nb) partial[tid] = acc - v;
        if (tid == 255) rowptr[n] = sm[255];
        return;
    }
    if (bid <= 20) {
        for (int idx = tid; idx < 960; idx += 256)
            ((float4*)smem)[idx] = ((const float4*)T)[idx];
        __syncthreads();
        int idx = (bid - 1) * 256 + tid;    // < 5120
        int i = idx / 40, j = idx - (idx / 40) * 40;
        float s = 0.f;
#pragma unroll 8
        for (int k = 0; k < 96; ++k) s = fmaf(W1[(size_t)i * 96 + k], smem[k * 40 + j], s);
        WF[idx] = s;
        return;
    }
    gemm_body<64, 40, float, float, 0>(dwe, Wfbot, nullptr, DW40, n,
                                       smem, smem + 2304, bid - 21, tid);
}

// local scan + rowptr/cursor + dinv
__global__ __launch_bounds__(256) void scan_p3(const int* __restrict__ cnt, const int* __restrict__ partial,
                                               int* __restrict__ rowptr, int* __restrict__ cursor,
                                               float* __restrict__ dinv, int n) {
    __shared__ int tsum[256];
    int tid = threadIdx.x;
    int base = blockIdx.x * 1024 + tid * 4;
    int v0 = 0, v1 = 0, v2 = 0, v3 = 0;
    if (base + 3 < n) {
        int4 t = *(const int4*)(cnt + base);
        v0 = t.x; v1 = t.y; v2 = t.z; v3 = t.w;
    } else {
        if (base + 0 < n) v0 = cnt[base + 0];
        if (base + 1 < n) v1 = cnt[base + 1];
        if (base + 2 < n) v2 = cnt[base + 2];
        if (base + 3 < n) v3 = cnt[base + 3];
    }
    int s = v0 + v1 + v2 + v3;
    tsum[tid] = s;
    __syncthreads();
    int acc = s;
    for (int off = 1; off < 256; off <<= 1) {
        int t = (tid >= off) ? tsum[tid - off] : 0;
        __syncthreads();
        acc += t;
        tsum[tid] = acc;
        __syncthreads();
    }
    int run = partial[blockIdx.x] + acc - s;
    int vv[4] = {v0, v1, v2, v3};
    for (int k = 0; k < 4; k++) {
        int i = base + k;
        if (i < n) {
            rowptr[i] = run; cursor[i] = run; run += vv[k];
            dinv[i] = rsqrtf((float)vv[k] + 1.0f);
        }
    }
}

// ---------------------------------------------------------------------------
// aggregation body. MODE: 1 = (acc*dv+bias)*dv (prescaled for next hop)
//                         2 = acc*dv+bias+extra32[i,f]  (h16 out)
//                         3 = sigmoid(acc*dv+bias+f2[i,f]+bfp[f]) -> f32 out
// 8x pipelined gathers for memory-level parallelism
// ---------------------------------------------------------------------------
template<int F, int MODE>
__device__ __forceinline__ void agg_body(
    const h16* __restrict__ hs, const int* __restrict__ rowptr,
    const int* __restrict__ col, const float* __restrict__ dinv,
    const float* __restrict__ bias, h16* __restrict__ out, int n,
    int bid, int tid,
    const float* __restrict__ extra32 = nullptr,
    const h16* __restrict__ f2 = nullptr,
    const float* __restrict__ bfp = nullptr,
    float* __restrict__ outf = nullptr)
{
    constexpr int F8 = F / 8;
    int gt = bid * 256 + tid;
    if (gt >= n * F8) return;
    int i = gt / F8;
    int f = gt - i * F8;
    int s = rowptr[i], e = rowptr[i + 1];
    const h16* base = hs + (size_t)f * 8;
    float acc[8];
    ld8h(hs + (size_t)i * F + f * 8, acc);
    int k = s;
    for (; k + 8 <= e; k += 8) {
        int c[8];
        union { uint4 u; h16 h[8]; } a[8];
#pragma unroll
        for (int q = 0; q < 8; ++q) c[q] = col[k + q];
#pragma unroll
        for (int q = 0; q < 8; ++q) a[q].u = *(const uint4*)(base + (size_t)c[q] * F);
#pragma unroll
        for (int j = 0; j < 8; ++j) {
            float t0 = ((float)a[0].h[j] + (float)a[1].h[j]) + ((float)a[2].h[j] + (float)a[3].h[j]);
            float t1 = ((float)a[4].h[j] + (float)a[5].h[j]) + ((float)a[6].h[j] + (float)a[7].h[j]);
            acc[j] += t0 + t1;
        }
    }
    for (; k + 4 <= e; k += 4) {
        int c0 = col[k], c1 = col[k + 1], c2 = col[k + 2], c3 = col[k + 3];
        union { uint4 u; h16 h[8]; } a0, a1, a2, a3;
        a0.u = *(const uint4*)(base + (size_t)c0 * F);
        a1.u = *(const uint4*)(base + (size_t)c1 * F);
        a2.u = *(const uint4*)(base + (size_t)c2 * F);
        a3.u = *(const uint4*)(base + (size_t)c3 * F);
#pragma unroll
        for (int j = 0; j < 8; ++j)
            acc[j] += ((float)a0.h[j] + (float)a1.h[j]) + ((float)a2.h[j] + (float)a3.h[j]);
    }
    for (; k < e; k++) {
        float v[8];
        ld8h(base + (size_t)col[k] * F, v);
#pragma unroll
        for (int j = 0; j < 8; ++j) acc[j] += v[j];
    }
    float dv = dinv[i];
    if constexpr (MODE == 3) {
        float fv[8];
        ld8h(f2 + (size_t)i * F + f * 8, fv);
        float r[8];
#pragma unroll
        for (int j = 0; j < 8; ++j) {
            float t = acc[j] * dv + bias[f * 8 + j] + fv[j] + bfp[f * 8 + j];
            r[j] = 1.f / (1.f + expf(-t));
        }
        float* po = outf + (size_t)i * F + f * 8;
        *(float4*)po       = make_float4(r[0], r[1], r[2], r[3]);
        *(float4*)(po + 4) = make_float4(r[4], r[5], r[6], r[7]);
    } else if constexpr (MODE == 2) {
        const float* pe = extra32 + (size_t)i * F + f * 8;
        float4 e0 = *(const float4*)pe;
        float4 e1 = *(const float4*)(pe + 4);
        float ex[8] = {e0.x, e0.y, e0.z, e0.w, e1.x, e1.y, e1.z, e1.w};
        union { uint4 u; h16 h[8]; } o;
#pragma unroll
        for (int j = 0; j < 8; ++j) o.h[j] = (h16)(acc[j] * dv + bias[f * 8 + j] + ex[j]);
        *(uint4*)(out + (size_t)i * F + f * 8) = o.u;
    } else {
        union { uint4 u; h16 h[8]; } o;
#pragma unroll
        for (int j = 0; j < 8; ++j) o.h[j] = (h16)((acc[j] * dv + bias[f * 8 + j]) * dv);
        *(uint4*)(out + (size_t)i * F + f * 8) = o.u;
    }
}

// plain prescaled hop (label hops 3..9)
__global__ __launch_bounds__(256) void agg40_pre_kernel(
    const h16* __restrict__ hs, const int* __restrict__ rowptr,
    const int* __restrict__ col, const float* __restrict__ dinv,
    const float* __restrict__ bias, h16* __restrict__ out, int n) {
    agg_body<40, 1>(hs, rowptr, col, dinv, bias, out, n, blockIdx.x, threadIdx.x);
}

// hop 1: label Z0->LA and feature F0->FB, both prescaled
__global__ __launch_bounds__(256) void agg_hop1_kernel(
    const h16* __restrict__ hsA, const float* __restrict__ biasA, h16* __restrict__ outA,
    const h16* __restrict__ hsB, const float* __restrict__ biasB, h16* __restrict__ outB,
    const int* __restrict__ rowptr, const int* __restrict__ col,
    const float* __restrict__ dinv, int n, int nblkA)
{
    if (blockIdx.x < nblkA)
        agg_body<40, 1>(hsA, rowptr, col, dinv, biasA, outA, n, blockIdx.x, threadIdx.x);
    else
        agg_body<40, 1>(hsB, rowptr, col, dinv, biasB, outB, n, blockIdx.x - nblkA, threadIdx.x);
}

// hop 2: label LA->LB (prescaled) + feature FB->F2 = agg + b2' + DW40
__global__ __launch_bounds__(256) void agg_hop2_kernel(
    const h16* __restrict__ hsA, const float* __restrict__ biasA, h16* __restrict__ outA,
    const h16* __restrict__ hsB, const float* __restrict__ biasB, h16* __restrict__ outB,
    const float* __restrict__ dw40,
    const int* __restrict__ rowptr, const int* __restrict__ col,
    const float* __restrict__ dinv, int n, int nblkA)
{
    if (blockIdx.x < nblkA)
        agg_body<40, 1>(hsA, rowptr, col, dinv, biasA, outA, n, blockIdx.x, threadIdx.x);
    else
        agg_body<40, 2>(hsB, rowptr, col, dinv, biasB, outB, n, blockIdx.x - nblkA, threadIdx.x, dw40);
}

// hop 10: out = sigmoid(agg(u9)+beta'10 + F2 + bf), f32 out
__global__ __launch_bounds__(256) void agg_final_kernel(
    const h16* __restrict__ hs, const int* __restrict__ rowptr,
    const int* __restrict__ col, const float* __restrict__ dinv,
    const float* __restrict__ bias, const h16* __restrict__ f2,
    const float* __restrict__ bf, float* __restrict__ outf, int n)
{
    agg_body<40, 3>(hs, rowptr, col, dinv, bias, nullptr, n, blockIdx.x, threadIdx.x,
                    nullptr, f2, bf, outf);
}

extern "C" void kernel_launch(void* const* d_in, const int* in_sizes, int n_in,
                              void* d_out, int out_size, void* d_ws, size_t ws_size,
                              hipStream_t stream) {
    const float* x   = (const float*)d_in[0];
    const float* y   = (const float*)d_in[1];
    const int*   ei  = (const int*)d_in[2];
    const float* dwe = (const float*)d_in[3];
    const float* W1  = (const float*)d_in[4];
    const float* b1  = (const float*)d_in[5];
    const float* W2  = (const float*)d_in[6];
    const float* b2  = (const float*)d_in[7];
    const float* Wl  = (const float*)d_in[8];
    const float* bl  = (const float*)d_in[9];
    const float* Wf  = (const float*)d_in[10];
    const float* bf  = (const float*)d_in[11];
    float* out = (float*)d_out;

    const int n = in_sizes[0] / 128;
    const int E = in_sizes[2] / 2;
    const int* srcp = ei;
    const int* dstp = ei + E;

    char* ws = (char*)d_ws;
    size_t off = 0;
    auto alloc = [&](size_t bytes) -> void* {
        void* p = ws + off;
        off += bytes;
        off = (off + 255) & ~(size_t)255;
        return p;
    };

    int*   cnt     = (int*)alloc((size_t)n * 4);
    float* dinv    = (float*)alloc((size_t)n * 4);
    int*   rowptr  = (int*)alloc((size_t)(n + 1) * 4);
    int*   cursor  = (int*)alloc((size_t)n * 4);
    int*   partial = (int*)alloc(256 * 4);
    int*   col     = (int*)alloc((size_t)E * 4);
    h16*   Z0      = (h16*)alloc((size_t)n * 40 * 2);
    h16*   LA      = (h16*)alloc((size_t)n * 40 * 2);
    h16*   LB      = (h16*)alloc((size_t)n * 40 * 2);
    h16*   F0      = (h16*)alloc((size_t)n * 40 * 2);
    h16*   FB      = (h16*)alloc((size_t)n * 40 * 2);
    h16*   F2      = (h16*)alloc((size_t)n * 40 * 2);
    float* DW40    = (float*)alloc((size_t)n * 40 * 4);
    float* CM      = (float*)alloc(1600 * 4);
    float* betas   = (float*)alloc(10 * 40 * 4);
    float* T       = (float*)alloc(96 * 40 * 4);
    float* WF      = (float*)alloc(128 * 40 * 4);
    float* betaf1p = (float*)alloc(40 * 4);
    float* b2p     = (float*)alloc(40 * 4);
    (void)ws_size;

    const int NB      = (n + 1023) / 1024;
    const int gb_gm   = (n + 63) / 64;
    const int gb_a40  = (n * 5 + THREADS - 1) / THREADS;
    const int PART_BLOCKS = 2048;

    // ---- CSR build (XCD-partitioned atomics) + full weight collapse ----
    hipMemsetAsync(cnt, 0, (size_t)n * 4, stream);
    count_part_kernel<<<PART_BLOCKS, THREADS, 0, stream>>>(dstp, cnt, E, n);
    scanp1_pre_kernel<<<NB + 16, THREADS, 0, stream>>>(
        cnt, partial, n, NB, Wl, bl, W2, b1, b2, Wf, CM, betas, T, betaf1p, b2p);
    scanp2_wf_dw_kernel<<<21 + gb_gm, THREADS, 0, stream>>>(
        partial, rowptr, NB, n, W1, T, WF, dwe, Wf + 136 * 40, DW40);
    scan_p3<<<NB, THREADS, 0, stream>>>(cnt, partial, rowptr, cursor, dinv, n);

    // ---- scatter + both input GEMMs in one dispatch (mutually independent) ----
    scatter_gemms_kernel<<<PART_BLOCKS + 2 * gb_gm, THREADS, 0, stream>>>(
        srcp, dstp, cursor, col, E, n, PART_BLOCKS, gb_gm,
        y, CM, Z0, x, WF, F0, dinv);

    // ---- hop 1: label + feature (both 40-wide, prescaled) ----
    agg_hop1_kernel<<<2 * gb_a40, THREADS, 0, stream>>>(
        Z0, betas + 0, LA, F0, betaf1p, FB, rowptr, col, dinv, n, gb_a40);
    // ---- hop 2: label + feature-final (F2 = agg + b2' + DW40) ----
    agg_hop2_kernel<<<2 * gb_a40, THREADS, 0, stream>>>(
        LA, betas + 40, LB, FB, b2p, F2, DW40, rowptr, col, dinv, n, gb_a40);

    // ---- label hops 3..9 (ping-pong) ----
    const h16* cur = LB;
    for (int m = 3; m <= 9; m++) {
        h16* nxt = (m & 1) ? LA : LB;
        agg40_pre_kernel<<<gb_a40, THREADS, 0, stream>>>(
            cur, rowptr, col, dinv, betas + (size_t)(m - 1) * 40, nxt, n);
        cur = nxt;
    }

    // ---- hop 10 + fuse + sigmoid, writes d_out directly ----
    agg_final_kernel<<<gb_a40, THREADS, 0, stream>>>(
        cur, rowptr, col, dinv, betas + 9 * 40, F2, bf, out, n);
}

// Round 19
// 347.094 us; speedup vs baseline: 1.0745x; 1.0745x over previous
//
#include <hip/hip_runtime.h>
#include <hip/hip_bf16.h>
#include <math.h>

#define THREADS 256
typedef _Float16 h16;

__device__ __forceinline__ void ld8h(const h16* p, float* f) {
    union { uint4 u; h16 h[8]; } c;
    c.u = *(const uint4*)p;
#pragma unroll
    for (int j = 0; j < 8; ++j) f[j] = (float)c.h[j];
}

// ---------------------------------------------------------------------------
// XCD-partitioned histogram / scatter (atomics stay L2-local per dst range)
// ---------------------------------------------------------------------------
__global__ __launch_bounds__(256) void count_part_kernel(
    const int* __restrict__ dst, int* __restrict__ cnt, int E, int n)
{
    const int cls = blockIdx.x & 7;
    const int nb  = gridDim.x >> 3;
    const int sub = blockIdx.x >> 3;
    const int lo = (int)((long long)n * cls / 8);
    const int hi = (int)((long long)n * (cls + 1) / 8);
    const int stride = nb * 256;
    for (int e = sub * 256 + threadIdx.x; e < E; e += stride) {
        int d = dst[e];
        if (d >= lo && d < hi) atomicAdd(&cnt[d], 1);
    }
}

__global__ __launch_bounds__(256) void scatter_part_kernel(
    const int* __restrict__ src, const int* __restrict__ dst,
    int* __restrict__ cursor, int* __restrict__ col, int E, int n)
{
    const int cls = blockIdx.x & 7;
    const int nb  = gridDim.x >> 3;
    const int sub = blockIdx.x >> 3;
    const int lo = (int)((long long)n * cls / 8);
    const int hi = (int)((long long)n * (cls + 1) / 8);
    const int stride = nb * 256;
    for (int e = sub * 256 + threadIdx.x; e < E; e += stride) {
        int d = dst[e];
        if (d >= lo && d < hi) {
            int p = atomicAdd(&cursor[d], 1);
            col[p] = src[e];
        }
    }
}

// ---------------------------------------------------------------------------
// scan_p1 (blocks [0,NB)) + weight collapse:
//   block NB: chain C~_m = W_{m+1}@C~_{m+1} (C~_10 = Wfmid), beta'_m = b_m@C~_m,
//             then betaf1' = (b1@W2)@Wf1, b2' = b2@Wf1
//   blocks NB+1..NB+15: T = W2@Wf1 (3840 elems, parallel)
// ---------------------------------------------------------------------------
__global__ __launch_bounds__(256) void scanp1_pre_kernel(
    const int* __restrict__ cnt, int* __restrict__ partial, int n, int NB,
    const float* __restrict__ Wl, const float* __restrict__ bl,
    const float* __restrict__ W2, const float* __restrict__ b1,
    const float* __restrict__ b2, const float* __restrict__ Wf,
    float* __restrict__ CM, float* __restrict__ betas,
    float* __restrict__ T, float* __restrict__ betaf1p, float* __restrict__ b2p)
{
    __shared__ __align__(16) float smem[5200];   // 20.8 KB (chain needs most)
    const int tid = threadIdx.x;
    const int bid = blockIdx.x;

    if (bid < NB) {
        int* red = (int*)smem;
        int base = bid * 1024 + tid * 4;
        int s = 0;
        if (base + 3 < n) {
            int4 v = *(const int4*)(cnt + base);
            s = v.x + v.y + v.z + v.w;
        } else {
            for (int k = 0; k < 4; k++) { int i = base + k; if (i < n) s += cnt[i]; }
        }
        red[tid] = s;
        __syncthreads();
        for (int off = 128; off > 0; off >>= 1) {
            if (tid < off) red[tid] += red[tid + off];
            __syncthreads();
        }
        if (tid == 0) partial[bid] = red[0];
        return;
    }

    if (bid == NB) {
        // ---- chain block ----
        float* Ca  = smem;            // 1600
        float* Cb  = smem + 1600;     // 1600
        float* sWm = smem + 3200;     // 1600
        float* bls = smem + 4800;     // 400
        for (int idx = tid; idx < 100; idx += 256)
            ((float4*)bls)[idx] = ((const float4*)bl)[idx];
        for (int idx = tid; idx < 400; idx += 256)
            ((float4*)Ca)[idx] = ((const float4*)(Wf + 3840))[idx];   // C~_10 = Wfmid
        __syncthreads();
        if (tid < 40) {   // beta'_10 = b_10 @ Wfmid
            float s = 0.f;
#pragma unroll
            for (int k = 0; k < 40; ++k) s = fmaf(bls[360 + k], Ca[k * 40 + tid], s);
            betas[360 + tid] = s;
        }
        __syncthreads();
        float* cur = Ca;
        float* nxt = Cb;
        for (int m = 9; m >= 0; --m) {
            for (int idx = tid; idx < 400; idx += 256)
                ((float4*)sWm)[idx] = ((const float4*)(Wl + (size_t)m * 1600))[idx];
            __syncthreads();
            for (int sid = tid; sid < 400; sid += 256) {
                int i = sid / 10, jq = sid - (sid / 10) * 10;
                const float4* wr4 = (const float4*)&sWm[i * 40];
                const float4* c4 = (const float4*)cur;
                float4 a = make_float4(0.f, 0.f, 0.f, 0.f);
#pragma unroll
                for (int k4 = 0; k4 < 10; ++k4) {
                    float4 w = wr4[k4];
                    float4 c0 = c4[(k4 * 4 + 0) * 10 + jq];
                    float4 c1 = c4[(k4 * 4 + 1) * 10 + jq];
                    float4 c2 = c4[(k4 * 4 + 2) * 10 + jq];
                    float4 c3 = c4[(k4 * 4 + 3) * 10 + jq];
                    a.x = fmaf(w.x, c0.x, fmaf(w.y, c1.x, fmaf(w.z, c2.x, fmaf(w.w, c3.x, a.x))));
                    a.y = fmaf(w.x, c0.y, fmaf(w.y, c1.y, fmaf(w.z, c2.y, fmaf(w.w, c3.y, a.y))));
                    a.z = fmaf(w.x, c0.z, fmaf(w.y, c1.z, fmaf(w.z, c2.z, fmaf(w.w, c3.z, a.z))));
                    a.w = fmaf(w.x, c0.w, fmaf(w.y, c1.w, fmaf(w.z, c2.w, fmaf(w.w, c3.w, a.w))));
                }
                ((float4*)nxt)[sid] = a;
            }
            __syncthreads();
            if (m >= 1 && tid < 40) {
                float s = 0.f;
                const float* br = &bls[(m - 1) * 40];
#pragma unroll
                for (int k = 0; k < 40; ++k) s = fmaf(br[k], nxt[k * 40 + tid], s);
                betas[(size_t)(m - 1) * 40 + tid] = s;
            }
            float* t = cur; cur = nxt; nxt = t;
            __syncthreads();
        }
        for (int idx = tid; idx < 1600; idx += 256) CM[idx] = cur[idx];
        __syncthreads();

        // ---- betaf1' / b2' (Wf1 re-staged into freed smem) ----
        float* sWf1 = smem;           // 3840
        float* vq   = smem + 3840;    // 96
        for (int q2 = tid; q2 < 960; q2 += 256)
            ((float4*)sWf1)[q2] = ((const float4*)Wf)[q2];
        if (tid < 96) {               // vq = b1 @ W2 (global reads, coalesced)
            float s = 0.f;
            for (int k = 0; k < 96; ++k) s = fmaf(b1[k], W2[(size_t)k * 96 + tid], s);
            vq[tid] = s;
        }
        __syncthreads();
        if (tid < 40) {
            float s1 = 0.f, s2 = 0.f;
            for (int q = 0; q < 96; ++q) {
                float w = sWf1[q * 40 + tid];
                s1 = fmaf(vq[q], w, s1);
                s2 = fmaf(b2[q], w, s2);
            }
            betaf1p[tid] = s1;
            b2p[tid] = s2;
        }
        return;
    }

    // ---- T blocks: T[k][j] = sum_q W2[k][q] * Wf1[q][j] ----
    {
        int tb = bid - NB - 1;            // 0..14
        int idx = tb * 256 + tid;         // < 3840
        float* sWf1 = smem;
        for (int q2 = tid; q2 < 960; q2 += 256)
            ((float4*)sWf1)[q2] = ((const float4*)Wf)[q2];
        __syncthreads();
        int k = idx / 40, j = idx - (idx / 40) * 40;
        float s = 0.f;
#pragma unroll 8
        for (int q = 0; q < 96; ++q) s = fmaf(W2[(size_t)k * 96 + q], sWf1[q * 40 + j], s);
        T[idx] = s;
    }
}

// ---------------------------------------------------------------------------
// GEMM body: Y = (X @ W) [* dinv[i] if DODINV], TO out (pointer-passed smem)
// ---------------------------------------------------------------------------
template<int FIN, int FOUT, typename TX, typename TO, int DODINV>
__device__ __forceinline__ void gemm_body(
    const TX* __restrict__ X, const float* __restrict__ W,
    const float* __restrict__ dinv, TO* __restrict__ Y, int n,
    float* sX, float* sW, int bid, int tid)
{
    constexpr int KC = (FIN % 32 == 0) ? 32 : FIN;
    constexpr int NCHUNK = FIN / KC;
    constexpr int TN = (FOUT + 15) / 16;
    constexpr int BM = 64;
    constexpr int KP = KC + 4;

    const int tj = tid & 15;
    const int ti = tid >> 4;
    const int i0 = bid * BM;

    float acc[4][TN] = {};

    for (int c = 0; c < NCHUNK; ++c) {
        const int k0 = c * KC;
        __syncthreads();
        if constexpr (sizeof(TX) == 2) {
            constexpr int K8 = KC / 8;
            for (int v = tid; v < BM * K8; v += 256) {
                int r = v / K8, q = v - r * K8;
                int gi = i0 + r;
                float f[8] = {0.f, 0.f, 0.f, 0.f, 0.f, 0.f, 0.f, 0.f};
                if (gi < n) ld8h((const h16*)X + (size_t)gi * FIN + k0 + q * 8, f);
                float* p = &sX[r * KP + q * 8];
#pragma unroll
                for (int j = 0; j < 8; ++j) p[j] = f[j];
            }
        } else {
            constexpr int K4 = KC / 4;
            for (int v = tid; v < BM * K4; v += 256) {
                int r = v / K4, q = v - r * K4;
                int gi = i0 + r;
                float4 val = (gi < n) ? *(const float4*)((const float*)X + (size_t)gi * FIN + k0 + q * 4)
                                      : make_float4(0.f, 0.f, 0.f, 0.f);
                float* p = &sX[r * KP + q * 4];
                p[0] = val.x; p[1] = val.y; p[2] = val.z; p[3] = val.w;
            }
        }
        for (int v = tid; v < KC * FOUT; v += 256) {
            int kk = v / FOUT;
            int j = v - kk * FOUT;
            sW[j * KP + kk] = W[(size_t)(k0 + kk) * FOUT + j];
        }
        __syncthreads();
#pragma unroll
        for (int kk = 0; kk < KC; kk += 4) {
            float4 xv[4];
#pragma unroll
            for (int m = 0; m < 4; ++m)
                xv[m] = *(const float4*)&sX[(ti + 16 * m) * KP + kk];
#pragma unroll
            for (int u = 0; u < TN; ++u) {
                float4 wv = *(const float4*)&sW[(tj + 16 * u) * KP + kk];
#pragma unroll
                for (int m = 0; m < 4; ++m) {
                    acc[m][u] = fmaf(xv[m].x, wv.x, acc[m][u]);
                    acc[m][u] = fmaf(xv[m].y, wv.y, acc[m][u]);
                    acc[m][u] = fmaf(xv[m].z, wv.z, acc[m][u]);
                    acc[m][u] = fmaf(xv[m].w, wv.w, acc[m][u]);
                }
            }
        }
    }

#pragma unroll
    for (int m = 0; m < 4; ++m) {
        int gi = i0 + ti + 16 * m;
        if (gi >= n) continue;
        float dv = 1.f;
        if constexpr (DODINV) dv = dinv[gi];
#pragma unroll
        for (int u = 0; u < TN; ++u) {
            int j = tj + 16 * u;
            if (j < FOUT) Y[(size_t)gi * FOUT + j] = (TO)(acc[m][u] * dv);
        }
    }
}

template<int FIN, int FOUT, typename TX, typename TO, int DODINV>
__global__ __launch_bounds__(256) void gemm_kernel(
    const TX* __restrict__ X, const float* __restrict__ W,
    const float* __restrict__ dinv, TO* __restrict__ Y, int n)
{
    constexpr int KC = (FIN % 32 == 0) ? 32 : FIN;
    constexpr int KP = KC + 4;
    constexpr int TN = (FOUT + 15) / 16;
    __shared__ __align__(16) float smem[64 * KP + TN * 16 * KP];
    gemm_body<FIN, FOUT, TX, TO, DODINV>(X, W, dinv, Y, n, smem, smem + 64 * KP,
                                         blockIdx.x, threadIdx.x);
}

// ---------------------------------------------------------------------------
// scan_p2 (block 0) + WF = W1@T (blocks 1..20) + DW40 = dwe@Wfbot (blocks 21..)
// ---------------------------------------------------------------------------
__global__ __launch_bounds__(256) void scanp2_wf_dw_kernel(
    int* __restrict__ partial, int* __restrict__ rowptr, int nb, int n,
    const float* __restrict__ W1, const float* __restrict__ T, float* __restrict__ WF,
    const float* __restrict__ dwe, const float* __restrict__ Wfbot, float* __restrict__ DW40)
{
    __shared__ __align__(16) float smem[4032];   // 16.1 KB (gemm<64,40> needs most)
    const int tid = threadIdx.x;
    const int bid = blockIdx.x;
    if (bid == 0) {
        int* sm = (int*)smem;
        int v = (tid < nb) ? partial[tid] : 0;
        sm[tid] = v;
        __syncthreads();
        int acc = v;
        for (int off = 1; off < 256; off <<= 1) {
            int t = (tid >= off) ? sm[tid - off] : 0;
            __syncthreads();
            acc += t;
            sm[tid] = acc;
            __syncthreads();
        }
        if (tid < nb) partial[tid] = acc - v;
        if (tid == 255) rowptr[n] = sm[255];
        return;
    }
    if (bid <= 20) {
        for (int idx = tid; idx < 960; idx += 256)
            ((float4*)smem)[idx] = ((const float4*)T)[idx];
        __syncthreads();
        int idx = (bid - 1) * 256 + tid;    // < 5120
        int i = idx / 40, j = idx - (idx / 40) * 40;
        float s = 0.f;
#pragma unroll 8
        for (int k = 0; k < 96; ++k) s = fmaf(W1[(size_t)i * 96 + k], smem[k * 40 + j], s);
        WF[idx] = s;
        return;
    }
    gemm_body<64, 40, float, float, 0>(dwe, Wfbot, nullptr, DW40, n,
                                       smem, smem + 2304, bid - 21, tid);
}

// local scan + rowptr/cursor + dinv
__global__ __launch_bounds__(256) void scan_p3(const int* __restrict__ cnt, const int* __restrict__ partial,
                                               int* __restrict__ rowptr, int* __restrict__ cursor,
                                               float* __restrict__ dinv, int n) {
    __shared__ int tsum[256];
    int tid = threadIdx.x;
    int base = blockIdx.x * 1024 + tid * 4;
    int v0 = 0, v1 = 0, v2 = 0, v3 = 0;
    if (base + 3 < n) {
        int4 t = *(const int4*)(cnt + base);
        v0 = t.x; v1 = t.y; v2 = t.z; v3 = t.w;
    } else {
        if (base + 0 < n) v0 = cnt[base + 0];
        if (base + 1 < n) v1 = cnt[base + 1];
        if (base + 2 < n) v2 = cnt[base + 2];
        if (base + 3 < n) v3 = cnt[base + 3];
    }
    int s = v0 + v1 + v2 + v3;
    tsum[tid] = s;
    __syncthreads();
    int acc = s;
    for (int off = 1; off < 256; off <<= 1) {
        int t = (tid >= off) ? tsum[tid - off] : 0;
        __syncthreads();
        acc += t;
        tsum[tid] = acc;
        __syncthreads();
    }
    int run = partial[blockIdx.x] + acc - s;
    int vv[4] = {v0, v1, v2, v3};
    for (int k = 0; k < 4; k++) {
        int i = base + k;
        if (i < n) {
            rowptr[i] = run; cursor[i] = run; run += vv[k];
            dinv[i] = rsqrtf((float)vv[k] + 1.0f);
        }
    }
}

// ---------------------------------------------------------------------------
// aggregation body. MODE: 1 = (acc*dv+bias)*dv (prescaled for next hop)
//                         2 = acc*dv+bias+extra32[i,f]  (h16 out)
//                         3 = sigmoid(acc*dv+bias+f2[i,f]+bfp[f]) -> f32 out
// 8x pipelined gathers for memory-level parallelism
// ---------------------------------------------------------------------------
template<int F, int MODE>
__device__ __forceinline__ void agg_body(
    const h16* __restrict__ hs, const int* __restrict__ rowptr,
    const int* __restrict__ col, const float* __restrict__ dinv,
    const float* __restrict__ bias, h16* __restrict__ out, int n,
    int bid, int tid,
    const float* __restrict__ extra32 = nullptr,
    const h16* __restrict__ f2 = nullptr,
    const float* __restrict__ bfp = nullptr,
    float* __restrict__ outf = nullptr)
{
    constexpr int F8 = F / 8;
    int gt = bid * 256 + tid;
    if (gt >= n * F8) return;
    int i = gt / F8;
    int f = gt - i * F8;
    int s = rowptr[i], e = rowptr[i + 1];
    const h16* base = hs + (size_t)f * 8;
    float acc[8];
    ld8h(hs + (size_t)i * F + f * 8, acc);
    int k = s;
    for (; k + 8 <= e; k += 8) {
        int c[8];
        union { uint4 u; h16 h[8]; } a[8];
#pragma unroll
        for (int q = 0; q < 8; ++q) c[q] = col[k + q];
#pragma unroll
        for (int q = 0; q < 8; ++q) a[q].u = *(const uint4*)(base + (size_t)c[q] * F);
#pragma unroll
        for (int j = 0; j < 8; ++j) {
            float t0 = ((float)a[0].h[j] + (float)a[1].h[j]) + ((float)a[2].h[j] + (float)a[3].h[j]);
            float t1 = ((float)a[4].h[j] + (float)a[5].h[j]) + ((float)a[6].h[j] + (float)a[7].h[j]);
            acc[j] += t0 + t1;
        }
    }
    for (; k + 4 <= e; k += 4) {
        int c0 = col[k], c1 = col[k + 1], c2 = col[k + 2], c3 = col[k + 3];
        union { uint4 u; h16 h[8]; } a0, a1, a2, a3;
        a0.u = *(const uint4*)(base + (size_t)c0 * F);
        a1.u = *(const uint4*)(base + (size_t)c1 * F);
        a2.u = *(const uint4*)(base + (size_t)c2 * F);
        a3.u = *(const uint4*)(base + (size_t)c3 * F);
#pragma unroll
        for (int j = 0; j < 8; ++j)
            acc[j] += ((float)a0.h[j] + (float)a1.h[j]) + ((float)a2.h[j] + (float)a3.h[j]);
    }
    for (; k < e; k++) {
        float v[8];
        ld8h(base + (size_t)col[k] * F, v);
#pragma unroll
        for (int j = 0; j < 8; ++j) acc[j] += v[j];
    }
    float dv = dinv[i];
    if constexpr (MODE == 3) {
        float fv[8];
        ld8h(f2 + (size_t)i * F + f * 8, fv);
        float r[8];
#pragma unroll
        for (int j = 0; j < 8; ++j) {
            float t = acc[j] * dv + bias[f * 8 + j] + fv[j] + bfp[f * 8 + j];
            r[j] = 1.f / (1.f + expf(-t));
        }
        float* po = outf + (size_t)i * F + f * 8;
        *(float4*)po       = make_float4(r[0], r[1], r[2], r[3]);
        *(float4*)(po + 4) = make_float4(r[4], r[5], r[6], r[7]);
    } else if constexpr (MODE == 2) {
        const float* pe = extra32 + (size_t)i * F + f * 8;
        float4 e0 = *(const float4*)pe;
        float4 e1 = *(const float4*)(pe + 4);
        float ex[8] = {e0.x, e0.y, e0.z, e0.w, e1.x, e1.y, e1.z, e1.w};
        union { uint4 u; h16 h[8]; } o;
#pragma unroll
        for (int j = 0; j < 8; ++j) o.h[j] = (h16)(acc[j] * dv + bias[f * 8 + j] + ex[j]);
        *(uint4*)(out + (size_t)i * F + f * 8) = o.u;
    } else {
        union { uint4 u; h16 h[8]; } o;
#pragma unroll
        for (int j = 0; j < 8; ++j) o.h[j] = (h16)((acc[j] * dv + bias[f * 8 + j]) * dv);
        *(uint4*)(out + (size_t)i * F + f * 8) = o.u;
    }
}

// plain prescaled hop (label hops 3..9)
__global__ __launch_bounds__(256) void agg40_pre_kernel(
    const h16* __restrict__ hs, const int* __restrict__ rowptr,
    const int* __restrict__ col, const float* __restrict__ dinv,
    const float* __restrict__ bias, h16* __restrict__ out, int n) {
    agg_body<40, 1>(hs, rowptr, col, dinv, bias, out, n, blockIdx.x, threadIdx.x);
}

// hop 1: label Z0->LA and feature F0->FB, both prescaled
__global__ __launch_bounds__(256) void agg_hop1_kernel(
    const h16* __restrict__ hsA, const float* __restrict__ biasA, h16* __restrict__ outA,
    const h16* __restrict__ hsB, const float* __restrict__ biasB, h16* __restrict__ outB,
    const int* __restrict__ rowptr, const int* __restrict__ col,
    const float* __restrict__ dinv, int n, int nblkA)
{
    if (blockIdx.x < nblkA)
        agg_body<40, 1>(hsA, rowptr, col, dinv, biasA, outA, n, blockIdx.x, threadIdx.x);
    else
        agg_body<40, 1>(hsB, rowptr, col, dinv, biasB, outB, n, blockIdx.x - nblkA, threadIdx.x);
}

// hop 2: label LA->LB (prescaled) + feature FB->F2 = agg + b2' + DW40
__global__ __launch_bounds__(256) void agg_hop2_kernel(
    const h16* __restrict__ hsA, const float* __restrict__ biasA, h16* __restrict__ outA,
    const h16* __restrict__ hsB, const float* __restrict__ biasB, h16* __restrict__ outB,
    const float* __restrict__ dw40,
    const int* __restrict__ rowptr, const int* __restrict__ col,
    const float* __restrict__ dinv, int n, int nblkA)
{
    if (blockIdx.x < nblkA)
        agg_body<40, 1>(hsA, rowptr, col, dinv, biasA, outA, n, blockIdx.x, threadIdx.x);
    else
        agg_body<40, 2>(hsB, rowptr, col, dinv, biasB, outB, n, blockIdx.x - nblkA, threadIdx.x, dw40);
}

// hop 10: out = sigmoid(agg(u9)+beta'10 + F2 + bf), f32 out
__global__ __launch_bounds__(256) void agg_final_kernel(
    const h16* __restrict__ hs, const int* __restrict__ rowptr,
    const int* __restrict__ col, const float* __restrict__ dinv,
    const float* __restrict__ bias, const h16* __restrict__ f2,
    const float* __restrict__ bf, float* __restrict__ outf, int n)
{
    agg_body<40, 3>(hs, rowptr, col, dinv, bias, nullptr, n, blockIdx.x, threadIdx.x,
                    nullptr, f2, bf, outf);
}

extern "C" void kernel_launch(void* const* d_in, const int* in_sizes, int n_in,
                              void* d_out, int out_size, void* d_ws, size_t ws_size,
                              hipStream_t stream) {
    const float* x   = (const float*)d_in[0];
    const float* y   = (const float*)d_in[1];
    const int*   ei  = (const int*)d_in[2];
    const float* dwe = (const float*)d_in[3];
    const float* W1  = (const float*)d_in[4];
    const float* b1  = (const float*)d_in[5];
    const float* W2  = (const float*)d_in[6];
    const float* b2  = (const float*)d_in[7];
    const float* Wl  = (const float*)d_in[8];
    const float* bl  = (const float*)d_in[9];
    const float* Wf  = (const float*)d_in[10];
    const float* bf  = (const float*)d_in[11];
    float* out = (float*)d_out;

    const int n = in_sizes[0] / 128;
    const int E = in_sizes[2] / 2;
    const int* srcp = ei;
    const int* dstp = ei + E;

    char* ws = (char*)d_ws;
    size_t off = 0;
    auto alloc = [&](size_t bytes) -> void* {
        void* p = ws + off;
        off += bytes;
        off = (off + 255) & ~(size_t)255;
        return p;
    };

    int*   cnt     = (int*)alloc((size_t)n * 4);
    float* dinv    = (float*)alloc((size_t)n * 4);
    int*   rowptr  = (int*)alloc((size_t)(n + 1) * 4);
    int*   cursor  = (int*)alloc((size_t)n * 4);
    int*   partial = (int*)alloc(256 * 4);
    int*   col     = (int*)alloc((size_t)E * 4);
    h16*   Z0      = (h16*)alloc((size_t)n * 40 * 2);
    h16*   LA      = (h16*)alloc((size_t)n * 40 * 2);
    h16*   LB      = (h16*)alloc((size_t)n * 40 * 2);
    h16*   F0      = (h16*)alloc((size_t)n * 40 * 2);
    h16*   FB      = (h16*)alloc((size_t)n * 40 * 2);
    h16*   F2      = (h16*)alloc((size_t)n * 40 * 2);
    float* DW40    = (float*)alloc((size_t)n * 40 * 4);
    float* CM      = (float*)alloc(1600 * 4);
    float* betas   = (float*)alloc(10 * 40 * 4);
    float* T       = (float*)alloc(96 * 40 * 4);
    float* WF      = (float*)alloc(128 * 40 * 4);
    float* betaf1p = (float*)alloc(40 * 4);
    float* b2p     = (float*)alloc(40 * 4);
    (void)ws_size;

    const int NB      = (n + 1023) / 1024;
    const int gb_gm   = (n + 63) / 64;
    const int gb_a40  = (n * 5 + THREADS - 1) / THREADS;
    const int PART_BLOCKS = 2048;

    // ---- CSR build (XCD-partitioned atomics) + full weight collapse ----
    hipMemsetAsync(cnt, 0, (size_t)n * 4, stream);
    count_part_kernel<<<PART_BLOCKS, THREADS, 0, stream>>>(dstp, cnt, E, n);
    scanp1_pre_kernel<<<NB + 16, THREADS, 0, stream>>>(
        cnt, partial, n, NB, Wl, bl, W2, b1, b2, Wf, CM, betas, T, betaf1p, b2p);
    scanp2_wf_dw_kernel<<<21 + gb_gm, THREADS, 0, stream>>>(
        partial, rowptr, NB, n, W1, T, WF, dwe, Wf + 136 * 40, DW40);
    scan_p3<<<NB, THREADS, 0, stream>>>(cnt, partial, rowptr, cursor, dinv, n);
    scatter_part_kernel<<<PART_BLOCKS, THREADS, 0, stream>>>(srcp, dstp, cursor, col, E, n);

    // ---- input GEMMs (label z0 and feature f0, 40-wide, prescaled) ----
    gemm_kernel<40, 40, float, h16, 1><<<gb_gm, THREADS, 0, stream>>>(y, CM, dinv, Z0, n);
    gemm_kernel<128, 40, float, h16, 1><<<gb_gm, THREADS, 0, stream>>>(x, WF, dinv, F0, n);

    // ---- hop 1: label + feature (both 40-wide, prescaled) ----
    agg_hop1_kernel<<<2 * gb_a40, THREADS, 0, stream>>>(
        Z0, betas + 0, LA, F0, betaf1p, FB, rowptr, col, dinv, n, gb_a40);
    // ---- hop 2: label + feature-final (F2 = agg + b2' + DW40) ----
    agg_hop2_kernel<<<2 * gb_a40, THREADS, 0, stream>>>(
        LA, betas + 40, LB, FB, b2p, F2, DW40, rowptr, col, dinv, n, gb_a40);

    // ---- label hops 3..9 (ping-pong) ----
    const h16* cur = LB;
    for (int m = 3; m <= 9; m++) {
        h16* nxt = (m & 1) ? LA : LB;
        agg40_pre_kernel<<<gb_a40, THREADS, 0, stream>>>(
            cur, rowptr, col, dinv, betas + (size_t)(m - 1) * 40, nxt, n);
        cur = nxt;
    }

    // ---- hop 10 + fuse + sigmoid, writes d_out directly ----
    agg_final_kernel<<<gb_a40, THREADS, 0, stream>>>(
        cur, rowptr, col, dinv, betas + 9 * 40, F2, bf, out, n);
}

// Round 20
// 344.501 us; speedup vs baseline: 1.0826x; 1.0075x over previous
//
#include <hip/hip_runtime.h>
#include <hip/hip_bf16.h>
#include <math.h>

#define THREADS 256
typedef _Float16 h16;
typedef unsigned short u16;

__device__ __forceinline__ void ld8h(const h16* p, float* f) {
    union { uint4 u; h16 h[8]; } c;
    c.u = *(const uint4*)p;
#pragma unroll
    for (int j = 0; j < 8; ++j) f[j] = (float)c.h[j];
}

// ---------------------------------------------------------------------------
// XCD-partitioned histogram / scatter (atomics stay L2-local per dst range)
// col stored as u16 (n < 65536): halves scatter writeback + hop col reads
// ---------------------------------------------------------------------------
__global__ __launch_bounds__(256) void count_part_kernel(
    const int* __restrict__ dst, int* __restrict__ cnt, int E, int n)
{
    const int cls = blockIdx.x & 7;
    const int nb  = gridDim.x >> 3;
    const int sub = blockIdx.x >> 3;
    const int lo = (int)((long long)n * cls / 8);
    const int hi = (int)((long long)n * (cls + 1) / 8);
    const int stride = nb * 256;
    for (int e = sub * 256 + threadIdx.x; e < E; e += stride) {
        int d = dst[e];
        if (d >= lo && d < hi) atomicAdd(&cnt[d], 1);
    }
}

__global__ __launch_bounds__(256) void scatter_part_kernel(
    const int* __restrict__ src, const int* __restrict__ dst,
    int* __restrict__ cursor, u16* __restrict__ col, int E, int n)
{
    const int cls = blockIdx.x & 7;
    const int nb  = gridDim.x >> 3;
    const int sub = blockIdx.x >> 3;
    const int lo = (int)((long long)n * cls / 8);
    const int hi = (int)((long long)n * (cls + 1) / 8);
    const int stride = nb * 256;
    for (int e = sub * 256 + threadIdx.x; e < E; e += stride) {
        int d = dst[e];
        if (d >= lo && d < hi) {
            int p = atomicAdd(&cursor[d], 1);
            col[p] = (u16)src[e];
        }
    }
}

// ---------------------------------------------------------------------------
// scan_p1 (blocks [0,NB)) + weight collapse:
//   block NB: chain C~_m = W_{m+1}@C~_{m+1} (C~_10 = Wfmid), beta'_m = b_m@C~_m,
//             then betaf1' = (b1@W2)@Wf1, b2' = b2@Wf1
//   blocks NB+1..NB+15: T = W2@Wf1 (3840 elems, parallel)
// ---------------------------------------------------------------------------
__global__ __launch_bounds__(256) void scanp1_pre_kernel(
    const int* __restrict__ cnt, int* __restrict__ partial, int n, int NB,
    const float* __restrict__ Wl, const float* __restrict__ bl,
    const float* __restrict__ W2, const float* __restrict__ b1,
    const float* __restrict__ b2, const float* __restrict__ Wf,
    float* __restrict__ CM, float* __restrict__ betas,
    float* __restrict__ T, float* __restrict__ betaf1p, float* __restrict__ b2p)
{
    __shared__ __align__(16) float smem[5200];   // 20.8 KB (chain needs most)
    const int tid = threadIdx.x;
    const int bid = blockIdx.x;

    if (bid < NB) {
        int* red = (int*)smem;
        int base = bid * 1024 + tid * 4;
        int s = 0;
        if (base + 3 < n) {
            int4 v = *(const int4*)(cnt + base);
            s = v.x + v.y + v.z + v.w;
        } else {
            for (int k = 0; k < 4; k++) { int i = base + k; if (i < n) s += cnt[i]; }
        }
        red[tid] = s;
        __syncthreads();
        for (int off = 128; off > 0; off >>= 1) {
            if (tid < off) red[tid] += red[tid + off];
            __syncthreads();
        }
        if (tid == 0) partial[bid] = red[0];
        return;
    }

    if (bid == NB) {
        // ---- chain block ----
        float* Ca  = smem;            // 1600
        float* Cb  = smem + 1600;     // 1600
        float* sWm = smem + 3200;     // 1600
        float* bls = smem + 4800;     // 400
        for (int idx = tid; idx < 100; idx += 256)
            ((float4*)bls)[idx] = ((const float4*)bl)[idx];
        for (int idx = tid; idx < 400; idx += 256)
            ((float4*)Ca)[idx] = ((const float4*)(Wf + 3840))[idx];   // C~_10 = Wfmid
        __syncthreads();
        if (tid < 40) {   // beta'_10 = b_10 @ Wfmid
            float s = 0.f;
#pragma unroll
            for (int k = 0; k < 40; ++k) s = fmaf(bls[360 + k], Ca[k * 40 + tid], s);
            betas[360 + tid] = s;
        }
        __syncthreads();
        float* cur = Ca;
        float* nxt = Cb;
        for (int m = 9; m >= 0; --m) {
            for (int idx = tid; idx < 400; idx += 256)
                ((float4*)sWm)[idx] = ((const float4*)(Wl + (size_t)m * 1600))[idx];
            __syncthreads();
            for (int sid = tid; sid < 400; sid += 256) {
                int i = sid / 10, jq = sid - (sid / 10) * 10;
                const float4* wr4 = (const float4*)&sWm[i * 40];
                const float4* c4 = (const float4*)cur;
                float4 a = make_float4(0.f, 0.f, 0.f, 0.f);
#pragma unroll
                for (int k4 = 0; k4 < 10; ++k4) {
                    float4 w = wr4[k4];
                    float4 c0 = c4[(k4 * 4 + 0) * 10 + jq];
                    float4 c1 = c4[(k4 * 4 + 1) * 10 + jq];
                    float4 c2 = c4[(k4 * 4 + 2) * 10 + jq];
                    float4 c3 = c4[(k4 * 4 + 3) * 10 + jq];
                    a.x = fmaf(w.x, c0.x, fmaf(w.y, c1.x, fmaf(w.z, c2.x, fmaf(w.w, c3.x, a.x))));
                    a.y = fmaf(w.x, c0.y, fmaf(w.y, c1.y, fmaf(w.z, c2.y, fmaf(w.w, c3.y, a.y))));
                    a.z = fmaf(w.x, c0.z, fmaf(w.y, c1.z, fmaf(w.z, c2.z, fmaf(w.w, c3.z, a.z))));
                    a.w = fmaf(w.x, c0.w, fmaf(w.y, c1.w, fmaf(w.z, c2.w, fmaf(w.w, c3.w, a.w))));
                }
                ((float4*)nxt)[sid] = a;
            }
            __syncthreads();
            if (m >= 1 && tid < 40) {
                float s = 0.f;
                const float* br = &bls[(m - 1) * 40];
#pragma unroll
                for (int k = 0; k < 40; ++k) s = fmaf(br[k], nxt[k * 40 + tid], s);
                betas[(size_t)(m - 1) * 40 + tid] = s;
            }
            float* t = cur; cur = nxt; nxt = t;
            __syncthreads();
        }
        for (int idx = tid; idx < 1600; idx += 256) CM[idx] = cur[idx];
        __syncthreads();

        // ---- betaf1' / b2' (Wf1 re-staged into freed smem) ----
        float* sWf1 = smem;           // 3840
        float* vq   = smem + 3840;    // 96
        for (int q2 = tid; q2 < 960; q2 += 256)
            ((float4*)sWf1)[q2] = ((const float4*)Wf)[q2];
        if (tid < 96) {               // vq = b1 @ W2 (global reads, coalesced)
            float s = 0.f;
            for (int k = 0; k < 96; ++k) s = fmaf(b1[k], W2[(size_t)k * 96 + tid], s);
            vq[tid] = s;
        }
        __syncthreads();
        if (tid < 40) {
            float s1 = 0.f, s2 = 0.f;
            for (int q = 0; q < 96; ++q) {
                float w = sWf1[q * 40 + tid];
                s1 = fmaf(vq[q], w, s1);
                s2 = fmaf(b2[q], w, s2);
            }
            betaf1p[tid] = s1;
            b2p[tid] = s2;
        }
        return;
    }

    // ---- T blocks: T[k][j] = sum_q W2[k][q] * Wf1[q][j] ----
    {
        int tb = bid - NB - 1;            // 0..14
        int idx = tb * 256 + tid;         // < 3840
        float* sWf1 = smem;
        for (int q2 = tid; q2 < 960; q2 += 256)
            ((float4*)sWf1)[q2] = ((const float4*)Wf)[q2];
        __syncthreads();
        int k = idx / 40, j = idx - (idx / 40) * 40;
        float s = 0.f;
#pragma unroll 8
        for (int q = 0; q < 96; ++q) s = fmaf(W2[(size_t)k * 96 + q], sWf1[q * 40 + j], s);
        T[idx] = s;
    }
}

// ---------------------------------------------------------------------------
// GEMM body: Y = (X @ W) [* dinv[i] if DODINV], TO out (pointer-passed smem)
// ---------------------------------------------------------------------------
template<int FIN, int FOUT, typename TX, typename TO, int DODINV>
__device__ __forceinline__ void gemm_body(
    const TX* __restrict__ X, const float* __restrict__ W,
    const float* __restrict__ dinv, TO* __restrict__ Y, int n,
    float* sX, float* sW, int bid, int tid)
{
    constexpr int KC = (FIN % 32 == 0) ? 32 : FIN;
    constexpr int NCHUNK = FIN / KC;
    constexpr int TN = (FOUT + 15) / 16;
    constexpr int BM = 64;
    constexpr int KP = KC + 4;

    const int tj = tid & 15;
    const int ti = tid >> 4;
    const int i0 = bid * BM;

    float acc[4][TN] = {};

    for (int c = 0; c < NCHUNK; ++c) {
        const int k0 = c * KC;
        __syncthreads();
        if constexpr (sizeof(TX) == 2) {
            constexpr int K8 = KC / 8;
            for (int v = tid; v < BM * K8; v += 256) {
                int r = v / K8, q = v - r * K8;
                int gi = i0 + r;
                float f[8] = {0.f, 0.f, 0.f, 0.f, 0.f, 0.f, 0.f, 0.f};
                if (gi < n) ld8h((const h16*)X + (size_t)gi * FIN + k0 + q * 8, f);
                float* p = &sX[r * KP + q * 8];
#pragma unroll
                for (int j = 0; j < 8; ++j) p[j] = f[j];
            }
        } else {
            constexpr int K4 = KC / 4;
            for (int v = tid; v < BM * K4; v += 256) {
                int r = v / K4, q = v - r * K4;
                int gi = i0 + r;
                float4 val = (gi < n) ? *(const float4*)((const float*)X + (size_t)gi * FIN + k0 + q * 4)
                                      : make_float4(0.f, 0.f, 0.f, 0.f);
                float* p = &sX[r * KP + q * 4];
                p[0] = val.x; p[1] = val.y; p[2] = val.z; p[3] = val.w;
            }
        }
        for (int v = tid; v < KC * FOUT; v += 256) {
            int kk = v / FOUT;
            int j = v - kk * FOUT;
            sW[j * KP + kk] = W[(size_t)(k0 + kk) * FOUT + j];
        }
        __syncthreads();
#pragma unroll
        for (int kk = 0; kk < KC; kk += 4) {
            float4 xv[4];
#pragma unroll
            for (int m = 0; m < 4; ++m)
                xv[m] = *(const float4*)&sX[(ti + 16 * m) * KP + kk];
#pragma unroll
            for (int u = 0; u < TN; ++u) {
                float4 wv = *(const float4*)&sW[(tj + 16 * u) * KP + kk];
#pragma unroll
                for (int m = 0; m < 4; ++m) {
                    acc[m][u] = fmaf(xv[m].x, wv.x, acc[m][u]);
                    acc[m][u] = fmaf(xv[m].y, wv.y, acc[m][u]);
                    acc[m][u] = fmaf(xv[m].z, wv.z, acc[m][u]);
                    acc[m][u] = fmaf(xv[m].w, wv.w, acc[m][u]);
                }
            }
        }
    }

#pragma unroll
    for (int m = 0; m < 4; ++m) {
        int gi = i0 + ti + 16 * m;
        if (gi >= n) continue;
        float dv = 1.f;
        if constexpr (DODINV) dv = dinv[gi];
#pragma unroll
        for (int u = 0; u < TN; ++u) {
            int j = tj + 16 * u;
            if (j < FOUT) Y[(size_t)gi * FOUT + j] = (TO)(acc[m][u] * dv);
        }
    }
}

template<int FIN, int FOUT, typename TX, typename TO, int DODINV>
__global__ __launch_bounds__(256) void gemm_kernel(
    const TX* __restrict__ X, const float* __restrict__ W,
    const float* __restrict__ dinv, TO* __restrict__ Y, int n)
{
    constexpr int KC = (FIN % 32 == 0) ? 32 : FIN;
    constexpr int KP = KC + 4;
    constexpr int TN = (FOUT + 15) / 16;
    __shared__ __align__(16) float smem[64 * KP + TN * 16 * KP];
    gemm_body<FIN, FOUT, TX, TO, DODINV>(X, W, dinv, Y, n, smem, smem + 64 * KP,
                                         blockIdx.x, threadIdx.x);
}

// ---------------------------------------------------------------------------
// scan_p2 (block 0) + WF = W1@T (blocks 1..20) + DW40 = dwe@Wfbot (blocks 21..)
// ---------------------------------------------------------------------------
__global__ __launch_bounds__(256) void scanp2_wf_dw_kernel(
    int* __restrict__ partial, int* __restrict__ rowptr, int nb, int n,
    const float* __restrict__ W1, const float* __restrict__ T, float* __restrict__ WF,
    const float* __restrict__ dwe, const float* __restrict__ Wfbot, float* __restrict__ DW40)
{
    __shared__ __align__(16) float smem[4032];   // 16.1 KB (gemm<64,40> needs most)
    const int tid = threadIdx.x;
    const int bid = blockIdx.x;
    if (bid == 0) {
        int* sm = (int*)smem;
        int v = (tid < nb) ? partial[tid] : 0;
        sm[tid] = v;
        __syncthreads();
        int acc = v;
        for (int off = 1; off < 256; off <<= 1) {
            int t = (tid >= off) ? sm[tid - off] : 0;
            __syncthreads();
            acc += t;
            sm[tid] = acc;
            __syncthreads();
        }
        if (tid < nb) partial[tid] = acc - v;
        if (tid == 255) rowptr[n] = sm[255];
        return;
    }
    if (bid <= 20) {
        for (int idx = tid; idx < 960; idx += 256)
            ((float4*)smem)[idx] = ((const float4*)T)[idx];
        __syncthreads();
        int idx = (bid - 1) * 256 + tid;    // < 5120
        int i = idx / 40, j = idx - (idx / 40) * 40;
        float s = 0.f;
#pragma unroll 8
        for (int k = 0; k < 96; ++k) s = fmaf(W1[(size_t)i * 96 + k], smem[k * 40 + j], s);
        WF[idx] = s;
        return;
    }
    gemm_body<64, 40, float, float, 0>(dwe, Wfbot, nullptr, DW40, n,
                                       smem, smem + 2304, bid - 21, tid);
}

// local scan + rowptr/cursor + dinv
__global__ __launch_bounds__(256) void scan_p3(const int* __restrict__ cnt, const int* __restrict__ partial,
                                               int* __restrict__ rowptr, int* __restrict__ cursor,
                                               float* __restrict__ dinv, int n) {
    __shared__ int tsum[256];
    int tid = threadIdx.x;
    int base = blockIdx.x * 1024 + tid * 4;
    int v0 = 0, v1 = 0, v2 = 0, v3 = 0;
    if (base + 3 < n) {
        int4 t = *(const int4*)(cnt + base);
        v0 = t.x; v1 = t.y; v2 = t.z; v3 = t.w;
    } else {
        if (base + 0 < n) v0 = cnt[base + 0];
        if (base + 1 < n) v1 = cnt[base + 1];
        if (base + 2 < n) v2 = cnt[base + 2];
        if (base + 3 < n) v3 = cnt[base + 3];
    }
    int s = v0 + v1 + v2 + v3;
    tsum[tid] = s;
    __syncthreads();
    int acc = s;
    for (int off = 1; off < 256; off <<= 1) {
        int t = (tid >= off) ? tsum[tid - off] : 0;
        __syncthreads();
        acc += t;
        tsum[tid] = acc;
        __syncthreads();
    }
    int run = partial[blockIdx.x] + acc - s;
    int vv[4] = {v0, v1, v2, v3};
    for (int k = 0; k < 4; k++) {
        int i = base + k;
        if (i < n) {
            rowptr[i] = run; cursor[i] = run; run += vv[k];
            dinv[i] = rsqrtf((float)vv[k] + 1.0f);
        }
    }
}

// ---------------------------------------------------------------------------
// aggregation body. MODE: 1 = (acc*dv+bias)*dv (prescaled for next hop)
//                         2 = acc*dv+bias+extra32[i,f]  (h16 out)
//                         3 = sigmoid(acc*dv+bias+f2[i,f]+bfp[f]) -> f32 out
// 8x pipelined gathers for memory-level parallelism; col is u16
// ---------------------------------------------------------------------------
template<int F, int MODE>
__device__ __forceinline__ void agg_body(
    const h16* __restrict__ hs, const int* __restrict__ rowptr,
    const u16* __restrict__ col, const float* __restrict__ dinv,
    const float* __restrict__ bias, h16* __restrict__ out, int n,
    int bid, int tid,
    const float* __restrict__ extra32 = nullptr,
    const h16* __restrict__ f2 = nullptr,
    const float* __restrict__ bfp = nullptr,
    float* __restrict__ outf = nullptr)
{
    constexpr int F8 = F / 8;
    int gt = bid * 256 + tid;
    if (gt >= n * F8) return;
    int i = gt / F8;
    int f = gt - i * F8;
    int s = rowptr[i], e = rowptr[i + 1];
    const h16* base = hs + (size_t)f * 8;
    float acc[8];
    ld8h(hs + (size_t)i * F + f * 8, acc);
    int k = s;
    for (; k + 8 <= e; k += 8) {
        int c[8];
        union { uint4 u; h16 h[8]; } a[8];
#pragma unroll
        for (int q = 0; q < 8; ++q) c[q] = (int)col[k + q];
#pragma unroll
        for (int q = 0; q < 8; ++q) a[q].u = *(const uint4*)(base + (size_t)c[q] * F);
#pragma unroll
        for (int j = 0; j < 8; ++j) {
            float t0 = ((float)a[0].h[j] + (float)a[1].h[j]) + ((float)a[2].h[j] + (float)a[3].h[j]);
            float t1 = ((float)a[4].h[j] + (float)a[5].h[j]) + ((float)a[6].h[j] + (float)a[7].h[j]);
            acc[j] += t0 + t1;
        }
    }
    for (; k + 4 <= e; k += 4) {
        int c0 = col[k], c1 = col[k + 1], c2 = col[k + 2], c3 = col[k + 3];
        union { uint4 u; h16 h[8]; } a0, a1, a2, a3;
        a0.u = *(const uint4*)(base + (size_t)c0 * F);
        a1.u = *(const uint4*)(base + (size_t)c1 * F);
        a2.u = *(const uint4*)(base + (size_t)c2 * F);
        a3.u = *(const uint4*)(base + (size_t)c3 * F);
#pragma unroll
        for (int j = 0; j < 8; ++j)
            acc[j] += ((float)a0.h[j] + (float)a1.h[j]) + ((float)a2.h[j] + (float)a3.h[j]);
    }
    for (; k < e; k++) {
        float v[8];
        ld8h(base + (size_t)col[k] * F, v);
#pragma unroll
        for (int j = 0; j < 8; ++j) acc[j] += v[j];
    }
    float dv = dinv[i];
    if constexpr (MODE == 3) {
        float fv[8];
        ld8h(f2 + (size_t)i * F + f * 8, fv);
        float r[8];
#pragma unroll
        for (int j = 0; j < 8; ++j) {
            float t = acc[j] * dv + bias[f * 8 + j] + fv[j] + bfp[f * 8 + j];
            r[j] = 1.f / (1.f + expf(-t));
        }
        float* po = outf + (size_t)i * F + f * 8;
        *(float4*)po       = make_float4(r[0], r[1], r[2], r[3]);
        *(float4*)(po + 4) = make_float4(r[4], r[5], r[6], r[7]);
    } else if constexpr (MODE == 2) {
        const float* pe = extra32 + (size_t)i * F + f * 8;
        float4 e0 = *(const float4*)pe;
        float4 e1 = *(const float4*)(pe + 4);
        float ex[8] = {e0.x, e0.y, e0.z, e0.w, e1.x, e1.y, e1.z, e1.w};
        union { uint4 u; h16 h[8]; } o;
#pragma unroll
        for (int j = 0; j < 8; ++j) o.h[j] = (h16)(acc[j] * dv + bias[f * 8 + j] + ex[j]);
        *(uint4*)(out + (size_t)i * F + f * 8) = o.u;
    } else {
        union { uint4 u; h16 h[8]; } o;
#pragma unroll
        for (int j = 0; j < 8; ++j) o.h[j] = (h16)((acc[j] * dv + bias[f * 8 + j]) * dv);
        *(uint4*)(out + (size_t)i * F + f * 8) = o.u;
    }
}

// plain prescaled hop (label hops 3..9)
__global__ __launch_bounds__(256) void agg40_pre_kernel(
    const h16* __restrict__ hs, const int* __restrict__ rowptr,
    const u16* __restrict__ col, const float* __restrict__ dinv,
    const float* __restrict__ bias, h16* __restrict__ out, int n) {
    agg_body<40, 1>(hs, rowptr, col, dinv, bias, out, n, blockIdx.x, threadIdx.x);
}

// hop 1: label Z0->LA and feature F0->FB, both prescaled
__global__ __launch_bounds__(256) void agg_hop1_kernel(
    const h16* __restrict__ hsA, const float* __restrict__ biasA, h16* __restrict__ outA,
    const h16* __restrict__ hsB, const float* __restrict__ biasB, h16* __restrict__ outB,
    const int* __restrict__ rowptr, const u16* __restrict__ col,
    const float* __restrict__ dinv, int n, int nblkA)
{
    if (blockIdx.x < nblkA)
        agg_body<40, 1>(hsA, rowptr, col, dinv, biasA, outA, n, blockIdx.x, threadIdx.x);
    else
        agg_body<40, 1>(hsB, rowptr, col, dinv, biasB, outB, n, blockIdx.x - nblkA, threadIdx.x);
}

// hop 2: label LA->LB (prescaled) + feature FB->F2 = agg + b2' + DW40
__global__ __launch_bounds__(256) void agg_hop2_kernel(
    const h16* __restrict__ hsA, const float* __restrict__ biasA, h16* __restrict__ outA,
    const h16* __restrict__ hsB, const float* __restrict__ biasB, h16* __restrict__ outB,
    const float* __restrict__ dw40,
    const int* __restrict__ rowptr, const u16* __restrict__ col,
    const float* __restrict__ dinv, int n, int nblkA)
{
    if (blockIdx.x < nblkA)
        agg_body<40, 1>(hsA, rowptr, col, dinv, biasA, outA, n, blockIdx.x, threadIdx.x);
    else
        agg_body<40, 2>(hsB, rowptr, col, dinv, biasB, outB, n, blockIdx.x - nblkA, threadIdx.x, dw40);
}

// hop 10: out = sigmoid(agg(u9)+beta'10 + F2 + bf), f32 out
__global__ __launch_bounds__(256) void agg_final_kernel(
    const h16* __restrict__ hs, const int* __restrict__ rowptr,
    const u16* __restrict__ col, const float* __restrict__ dinv,
    const float* __restrict__ bias, const h16* __restrict__ f2,
    const float* __restrict__ bf, float* __restrict__ outf, int n)
{
    agg_body<40, 3>(hs, rowptr, col, dinv, bias, nullptr, n, blockIdx.x, threadIdx.x,
                    nullptr, f2, bf, outf);
}

extern "C" void kernel_launch(void* const* d_in, const int* in_sizes, int n_in,
                              void* d_out, int out_size, void* d_ws, size_t ws_size,
                              hipStream_t stream) {
    const float* x   = (const float*)d_in[0];
    const float* y   = (const float*)d_in[1];
    const int*   ei  = (const int*)d_in[2];
    const float* dwe = (const float*)d_in[3];
    const float* W1  = (const float*)d_in[4];
    const float* b1  = (const float*)d_in[5];
    const float* W2  = (const float*)d_in[6];
    const float* b2  = (const float*)d_in[7];
    const float* Wl  = (const float*)d_in[8];
    const float* bl  = (const float*)d_in[9];
    const float* Wf  = (const float*)d_in[10];
    const float* bf  = (const float*)d_in[11];
    float* out = (float*)d_out;

    const int n = in_sizes[0] / 128;
    const int E = in_sizes[2] / 2;
    const int* srcp = ei;
    const int* dstp = ei + E;

    char* ws = (char*)d_ws;
    size_t off = 0;
    auto alloc = [&](size_t bytes) -> void* {
        void* p = ws + off;
        off += bytes;
        off = (off + 255) & ~(size_t)255;
        return p;
    };

    int*   cnt     = (int*)alloc((size_t)n * 4);
    float* dinv    = (float*)alloc((size_t)n * 4);
    int*   rowptr  = (int*)alloc((size_t)(n + 1) * 4);
    int*   cursor  = (int*)alloc((size_t)n * 4);
    int*   partial = (int*)alloc(256 * 4);
    u16*   col     = (u16*)alloc((size_t)E * 2);
    h16*   Z0      = (h16*)alloc((size_t)n * 40 * 2);
    h16*   LA      = (h16*)alloc((size_t)n * 40 * 2);
    h16*   LB      = (h16*)alloc((size_t)n * 40 * 2);
    h16*   F0      = (h16*)alloc((size_t)n * 40 * 2);
    h16*   FB      = (h16*)alloc((size_t)n * 40 * 2);
    h16*   F2      = (h16*)alloc((size_t)n * 40 * 2);
    float* DW40    = (float*)alloc((size_t)n * 40 * 4);
    float* CM      = (float*)alloc(1600 * 4);
    float* betas   = (float*)alloc(10 * 40 * 4);
    float* T       = (float*)alloc(96 * 40 * 4);
    float* WF      = (float*)alloc(128 * 40 * 4);
    float* betaf1p = (float*)alloc(40 * 4);
    float* b2p     = (float*)alloc(40 * 4);
    (void)ws_size;

    const int NB      = (n + 1023) / 1024;
    const int gb_gm   = (n + 63) / 64;
    const int gb_a40  = (n * 5 + THREADS - 1) / THREADS;
    const int PART_BLOCKS = 2048;

    // ---- CSR build (XCD-partitioned atomics) + full weight collapse ----
    hipMemsetAsync(cnt, 0, (size_t)n * 4, stream);
    count_part_kernel<<<PART_BLOCKS, THREADS, 0, stream>>>(dstp, cnt, E, n);
    scanp1_pre_kernel<<<NB + 16, THREADS, 0, stream>>>(
        cnt, partial, n, NB, Wl, bl, W2, b1, b2, Wf, CM, betas, T, betaf1p, b2p);
    scanp2_wf_dw_kernel<<<21 + gb_gm, THREADS, 0, stream>>>(
        partial, rowptr, NB, n, W1, T, WF, dwe, Wf + 136 * 40, DW40);
    scan_p3<<<NB, THREADS, 0, stream>>>(cnt, partial, rowptr, cursor, dinv, n);
    scatter_part_kernel<<<PART_BLOCKS, THREADS, 0, stream>>>(srcp, dstp, cursor, col, E, n);

    // ---- input GEMMs (label z0 and feature f0, 40-wide, prescaled) ----
    gemm_kernel<40, 40, float, h16, 1><<<gb_gm, THREADS, 0, stream>>>(y, CM, dinv, Z0, n);
    gemm_kernel<128, 40, float, h16, 1><<<gb_gm, THREADS, 0, stream>>>(x, WF, dinv, F0, n);

    // ---- hop 1: label + feature (both 40-wide, prescaled) ----
    agg_hop1_kernel<<<2 * gb_a40, THREADS, 0, stream>>>(
        Z0, betas + 0, LA, F0, betaf1p, FB, rowptr, col, dinv, n, gb_a40);
    // ---- hop 2: label + feature-final (F2 = agg + b2' + DW40) ----
    agg_hop2_kernel<<<2 * gb_a40, THREADS, 0, stream>>>(
        LA, betas + 40, LB, FB, b2p, F2, DW40, rowptr, col, dinv, n, gb_a40);

    // ---- label hops 3..9 (ping-pong) ----
    const h16* cur = LB;
    for (int m = 3; m <= 9; m++) {
        h16* nxt = (m & 1) ? LA : LB;
        agg40_pre_kernel<<<gb_a40, THREADS, 0, stream>>>(
            cur, rowptr, col, dinv, betas + (size_t)(m - 1) * 40, nxt, n);
        cur = nxt;
    }

    // ---- hop 10 + fuse + sigmoid, writes d_out directly ----
    agg_final_kernel<<<gb_a40, THREADS, 0, stream>>>(
        cur, rowptr, col, dinv, betas + 9 * 40, F2, bf, out, n);
}

// Round 21
// 341.536 us; speedup vs baseline: 1.0920x; 1.0087x over previous
//
#include <hip/hip_runtime.h>
#include <hip/hip_bf16.h>
#include <math.h>

#define THREADS 256
typedef _Float16 h16;
typedef unsigned short u16;

__device__ __forceinline__ void ld8h(const h16* p, float* f) {
    union { uint4 u; h16 h[8]; } c;
    c.u = *(const uint4*)p;
#pragma unroll
    for (int j = 0; j < 8; ++j) f[j] = (float)c.h[j];
}

// ---------------------------------------------------------------------------
// XCD-partitioned histogram / scatter (atomics stay L2-local per dst range)
// col stored as u16 (n < 65536): halves scatter writeback + hop col reads
// ---------------------------------------------------------------------------
__global__ __launch_bounds__(256) void count_part_kernel(
    const int* __restrict__ dst, int* __restrict__ cnt, int E, int n)
{
    const int cls = blockIdx.x & 7;
    const int nb  = gridDim.x >> 3;
    const int sub = blockIdx.x >> 3;
    const int lo = (int)((long long)n * cls / 8);
    const int hi = (int)((long long)n * (cls + 1) / 8);
    const int stride = nb * 256;
    for (int e = sub * 256 + threadIdx.x; e < E; e += stride) {
        int d = dst[e];
        if (d >= lo && d < hi) atomicAdd(&cnt[d], 1);
    }
}

__global__ __launch_bounds__(256) void scatter_part_kernel(
    const int* __restrict__ src, const int* __restrict__ dst,
    int* __restrict__ cursor, u16* __restrict__ col, int E, int n)
{
    const int cls = blockIdx.x & 7;
    const int nb  = gridDim.x >> 3;
    const int sub = blockIdx.x >> 3;
    const int lo = (int)((long long)n * cls / 8);
    const int hi = (int)((long long)n * (cls + 1) / 8);
    const int stride = nb * 256;
    for (int e = sub * 256 + threadIdx.x; e < E; e += stride) {
        int d = dst[e];
        if (d >= lo && d < hi) {
            int p = atomicAdd(&cursor[d], 1);
            col[p] = (u16)src[e];
        }
    }
}

// ---------------------------------------------------------------------------
// scan_p1 (blocks [0,NB)) + weight collapse:
//   block NB: chain C~_m = W_{m+1}@C~_{m+1} (C~_10 = Wfmid), beta'_m = b_m@C~_m,
//             then betaf1' = (b1@W2)@Wf1, b2' = b2@Wf1
//   blocks NB+1..NB+15: T = W2@Wf1 (3840 elems, parallel)
// ---------------------------------------------------------------------------
__global__ __launch_bounds__(256) void scanp1_pre_kernel(
    const int* __restrict__ cnt, int* __restrict__ partial, int n, int NB,
    const float* __restrict__ Wl, const float* __restrict__ bl,
    const float* __restrict__ W2, const float* __restrict__ b1,
    const float* __restrict__ b2, const float* __restrict__ Wf,
    float* __restrict__ CM, float* __restrict__ betas,
    float* __restrict__ T, float* __restrict__ betaf1p, float* __restrict__ b2p)
{
    __shared__ __align__(16) float smem[5200];   // 20.8 KB (chain needs most)
    const int tid = threadIdx.x;
    const int bid = blockIdx.x;

    if (bid < NB) {
        int* red = (int*)smem;
        int base = bid * 1024 + tid * 4;
        int s = 0;
        if (base + 3 < n) {
            int4 v = *(const int4*)(cnt + base);
            s = v.x + v.y + v.z + v.w;
        } else {
            for (int k = 0; k < 4; k++) { int i = base + k; if (i < n) s += cnt[i]; }
        }
        red[tid] = s;
        __syncthreads();
        for (int off = 128; off > 0; off >>= 1) {
            if (tid < off) red[tid] += red[tid + off];
            __syncthreads();
        }
        if (tid == 0) partial[bid] = red[0];
        return;
    }

    if (bid == NB) {
        // ---- chain block ----
        float* Ca  = smem;            // 1600
        float* Cb  = smem + 1600;     // 1600
        float* sWm = smem + 3200;     // 1600
        float* bls = smem + 4800;     // 400
        for (int idx = tid; idx < 100; idx += 256)
            ((float4*)bls)[idx] = ((const float4*)bl)[idx];
        for (int idx = tid; idx < 400; idx += 256)
            ((float4*)Ca)[idx] = ((const float4*)(Wf + 3840))[idx];   // C~_10 = Wfmid
        __syncthreads();
        if (tid < 40) {   // beta'_10 = b_10 @ Wfmid
            float s = 0.f;
#pragma unroll
            for (int k = 0; k < 40; ++k) s = fmaf(bls[360 + k], Ca[k * 40 + tid], s);
            betas[360 + tid] = s;
        }
        __syncthreads();
        float* cur = Ca;
        float* nxt = Cb;
        for (int m = 9; m >= 0; --m) {
            for (int idx = tid; idx < 400; idx += 256)
                ((float4*)sWm)[idx] = ((const float4*)(Wl + (size_t)m * 1600))[idx];
            __syncthreads();
            for (int sid = tid; sid < 400; sid += 256) {
                int i = sid / 10, jq = sid - (sid / 10) * 10;
                const float4* wr4 = (const float4*)&sWm[i * 40];
                const float4* c4 = (const float4*)cur;
                float4 a = make_float4(0.f, 0.f, 0.f, 0.f);
#pragma unroll
                for (int k4 = 0; k4 < 10; ++k4) {
                    float4 w = wr4[k4];
                    float4 c0 = c4[(k4 * 4 + 0) * 10 + jq];
                    float4 c1 = c4[(k4 * 4 + 1) * 10 + jq];
                    float4 c2 = c4[(k4 * 4 + 2) * 10 + jq];
                    float4 c3 = c4[(k4 * 4 + 3) * 10 + jq];
                    a.x = fmaf(w.x, c0.x, fmaf(w.y, c1.x, fmaf(w.z, c2.x, fmaf(w.w, c3.x, a.x))));
                    a.y = fmaf(w.x, c0.y, fmaf(w.y, c1.y, fmaf(w.z, c2.y, fmaf(w.w, c3.y, a.y))));
                    a.z = fmaf(w.x, c0.z, fmaf(w.y, c1.z, fmaf(w.z, c2.z, fmaf(w.w, c3.z, a.z))));
                    a.w = fmaf(w.x, c0.w, fmaf(w.y, c1.w, fmaf(w.z, c2.w, fmaf(w.w, c3.w, a.w))));
                }
                ((float4*)nxt)[sid] = a;
            }
            __syncthreads();
            if (m >= 1 && tid < 40) {
                float s = 0.f;
                const float* br = &bls[(m - 1) * 40];
#pragma unroll
                for (int k = 0; k < 40; ++k) s = fmaf(br[k], nxt[k * 40 + tid], s);
                betas[(size_t)(m - 1) * 40 + tid] = s;
            }
            float* t = cur; cur = nxt; nxt = t;
            __syncthreads();
        }
        for (int idx = tid; idx < 1600; idx += 256) CM[idx] = cur[idx];
        __syncthreads();

        // ---- betaf1' / b2' (Wf1 re-staged into freed smem) ----
        float* sWf1 = smem;           // 3840
        float* vq   = smem + 3840;    // 96
        for (int q2 = tid; q2 < 960; q2 += 256)
            ((float4*)sWf1)[q2] = ((const float4*)Wf)[q2];
        if (tid < 96) {               // vq = b1 @ W2 (global reads, coalesced)
            float s = 0.f;
            for (int k = 0; k < 96; ++k) s = fmaf(b1[k], W2[(size_t)k * 96 + tid], s);
            vq[tid] = s;
        }
        __syncthreads();
        if (tid < 40) {
            float s1 = 0.f, s2 = 0.f;
            for (int q = 0; q < 96; ++q) {
                float w = sWf1[q * 40 + tid];
                s1 = fmaf(vq[q], w, s1);
                s2 = fmaf(b2[q], w, s2);
            }
            betaf1p[tid] = s1;
            b2p[tid] = s2;
        }
        return;
    }

    // ---- T blocks: T[k][j] = sum_q W2[k][q] * Wf1[q][j] ----
    {
        int tb = bid - NB - 1;            // 0..14
        int idx = tb * 256 + tid;         // < 3840
        float* sWf1 = smem;
        for (int q2 = tid; q2 < 960; q2 += 256)
            ((float4*)sWf1)[q2] = ((const float4*)Wf)[q2];
        __syncthreads();
        int k = idx / 40, j = idx - (idx / 40) * 40;
        float s = 0.f;
#pragma unroll 8
        for (int q = 0; q < 96; ++q) s = fmaf(W2[(size_t)k * 96 + q], sWf1[q * 40 + j], s);
        T[idx] = s;
    }
}

// ---------------------------------------------------------------------------
// GEMM body: Y = (X @ W) [* dinv[i] if DODINV], TO out (pointer-passed smem)
// ---------------------------------------------------------------------------
template<int FIN, int FOUT, typename TX, typename TO, int DODINV>
__device__ __forceinline__ void gemm_body(
    const TX* __restrict__ X, const float* __restrict__ W,
    const float* __restrict__ dinv, TO* __restrict__ Y, int n,
    float* sX, float* sW, int bid, int tid)
{
    constexpr int KC = (FIN % 32 == 0) ? 32 : FIN;
    constexpr int NCHUNK = FIN / KC;
    constexpr int TN = (FOUT + 15) / 16;
    constexpr int BM = 64;
    constexpr int KP = KC + 4;

    const int tj = tid & 15;
    const int ti = tid >> 4;
    const int i0 = bid * BM;

    float acc[4][TN] = {};

    for (int c = 0; c < NCHUNK; ++c) {
        const int k0 = c * KC;
        __syncthreads();
        if constexpr (sizeof(TX) == 2) {
            constexpr int K8 = KC / 8;
            for (int v = tid; v < BM * K8; v += 256) {
                int r = v / K8, q = v - r * K8;
                int gi = i0 + r;
                float f[8] = {0.f, 0.f, 0.f, 0.f, 0.f, 0.f, 0.f, 0.f};
                if (gi < n) ld8h((const h16*)X + (size_t)gi * FIN + k0 + q * 8, f);
                float* p = &sX[r * KP + q * 8];
#pragma unroll
                for (int j = 0; j < 8; ++j) p[j] = f[j];
            }
        } else {
            constexpr int K4 = KC / 4;
            for (int v = tid; v < BM * K4; v += 256) {
                int r = v / K4, q = v - r * K4;
                int gi = i0 + r;
                float4 val = (gi < n) ? *(const float4*)((const float*)X + (size_t)gi * FIN + k0 + q * 4)
                                      : make_float4(0.f, 0.f, 0.f, 0.f);
                float* p = &sX[r * KP + q * 4];
                p[0] = val.x; p[1] = val.y; p[2] = val.z; p[3] = val.w;
            }
        }
        for (int v = tid; v < KC * FOUT; v += 256) {
            int kk = v / FOUT;
            int j = v - kk * FOUT;
            sW[j * KP + kk] = W[(size_t)(k0 + kk) * FOUT + j];
        }
        __syncthreads();
#pragma unroll
        for (int kk = 0; kk < KC; kk += 4) {
            float4 xv[4];
#pragma unroll
            for (int m = 0; m < 4; ++m)
                xv[m] = *(const float4*)&sX[(ti + 16 * m) * KP + kk];
#pragma unroll
            for (int u = 0; u < TN; ++u) {
                float4 wv = *(const float4*)&sW[(tj + 16 * u) * KP + kk];
#pragma unroll
                for (int m = 0; m < 4; ++m) {
                    acc[m][u] = fmaf(xv[m].x, wv.x, acc[m][u]);
                    acc[m][u] = fmaf(xv[m].y, wv.y, acc[m][u]);
                    acc[m][u] = fmaf(xv[m].z, wv.z, acc[m][u]);
                    acc[m][u] = fmaf(xv[m].w, wv.w, acc[m][u]);
                }
            }
        }
    }

#pragma unroll
    for (int m = 0; m < 4; ++m) {
        int gi = i0 + ti + 16 * m;
        if (gi >= n) continue;
        float dv = 1.f;
        if constexpr (DODINV) dv = dinv[gi];
#pragma unroll
        for (int u = 0; u < TN; ++u) {
            int j = tj + 16 * u;
            if (j < FOUT) Y[(size_t)gi * FOUT + j] = (TO)(acc[m][u] * dv);
        }
    }
}

template<int FIN, int FOUT, typename TX, typename TO, int DODINV>
__global__ __launch_bounds__(256) void gemm_kernel(
    const TX* __restrict__ X, const float* __restrict__ W,
    const float* __restrict__ dinv, TO* __restrict__ Y, int n)
{
    constexpr int KC = (FIN % 32 == 0) ? 32 : FIN;
    constexpr int KP = KC + 4;
    constexpr int TN = (FOUT + 15) / 16;
    __shared__ __align__(16) float smem[64 * KP + TN * 16 * KP];
    gemm_body<FIN, FOUT, TX, TO, DODINV>(X, W, dinv, Y, n, smem, smem + 64 * KP,
                                         blockIdx.x, threadIdx.x);
}

// ---------------------------------------------------------------------------
// scan_p2 (block 0) + WF = W1@T (blocks 1..20) + DW40 = dwe@Wfbot (blocks 21..)
// ---------------------------------------------------------------------------
__global__ __launch_bounds__(256) void scanp2_wf_dw_kernel(
    int* __restrict__ partial, int* __restrict__ rowptr, int nb, int n,
    const float* __restrict__ W1, const float* __restrict__ T, float* __restrict__ WF,
    const float* __restrict__ dwe, const float* __restrict__ Wfbot, float* __restrict__ DW40)
{
    __shared__ __align__(16) float smem[4032];   // 16.1 KB (gemm<64,40> needs most)
    const int tid = threadIdx.x;
    const int bid = blockIdx.x;
    if (bid == 0) {
        int* sm = (int*)smem;
        int v = (tid < nb) ? partial[tid] : 0;
        sm[tid] = v;
        __syncthreads();
        int acc = v;
        for (int off = 1; off < 256; off <<= 1) {
            int t = (tid >= off) ? sm[tid - off] : 0;
            __syncthreads();
            acc += t;
            sm[tid] = acc;
            __syncthreads();
        }
        if (tid < nb) partial[tid] = acc - v;
        if (tid == 255) rowptr[n] = sm[255];
        return;
    }
    if (bid <= 20) {
        for (int idx = tid; idx < 960; idx += 256)
            ((float4*)smem)[idx] = ((const float4*)T)[idx];
        __syncthreads();
        int idx = (bid - 1) * 256 + tid;    // < 5120
        int i = idx / 40, j = idx - (idx / 40) * 40;
        float s = 0.f;
#pragma unroll 8
        for (int k = 0; k < 96; ++k) s = fmaf(W1[(size_t)i * 96 + k], smem[k * 40 + j], s);
        WF[idx] = s;
        return;
    }
    gemm_body<64, 40, float, float, 0>(dwe, Wfbot, nullptr, DW40, n,
                                       smem, smem + 2304, bid - 21, tid);
}

// local scan + rowptr/cursor + dinv
__global__ __launch_bounds__(256) void scan_p3(const int* __restrict__ cnt, const int* __restrict__ partial,
                                               int* __restrict__ rowptr, int* __restrict__ cursor,
                                               float* __restrict__ dinv, int n) {
    __shared__ int tsum[256];
    int tid = threadIdx.x;
    int base = blockIdx.x * 1024 + tid * 4;
    int v0 = 0, v1 = 0, v2 = 0, v3 = 0;
    if (base + 3 < n) {
        int4 t = *(const int4*)(cnt + base);
        v0 = t.x; v1 = t.y; v2 = t.z; v3 = t.w;
    } else {
        if (base + 0 < n) v0 = cnt[base + 0];
        if (base + 1 < n) v1 = cnt[base + 1];
        if (base + 2 < n) v2 = cnt[base + 2];
        if (base + 3 < n) v3 = cnt[base + 3];
    }
    int s = v0 + v1 + v2 + v3;
    tsum[tid] = s;
    __syncthreads();
    int acc = s;
    for (int off = 1; off < 256; off <<= 1) {
        int t = (tid >= off) ? tsum[tid - off] : 0;
        __syncthreads();
        acc += t;
        tsum[tid] = acc;
        __syncthreads();
    }
    int run = partial[blockIdx.x] + acc - s;
    int vv[4] = {v0, v1, v2, v3};
    for (int k = 0; k < 4; k++) {
        int i = base + k;
        if (i < n) {
            rowptr[i] = run; cursor[i] = run; run += vv[k];
            dinv[i] = rsqrtf((float)vv[k] + 1.0f);
        }
    }
}

// ---------------------------------------------------------------------------
// aggregation body. MODE: 1 = (acc*dv+bias)*dv (prescaled for next hop)
//                         2 = acc*dv+bias+extra32[i,f]  (h16 out)
//                         3 = sigmoid(acc*dv+bias+f2[i,f]+bfp[f]) -> f32 out
// 8x pipelined gathers for memory-level parallelism; col is u16
// ---------------------------------------------------------------------------
template<int F, int MODE>
__device__ __forceinline__ void agg_body(
    const h16* __restrict__ hs, const int* __restrict__ rowptr,
    const u16* __restrict__ col, const float* __restrict__ dinv,
    const float* __restrict__ bias, h16* __restrict__ out, int n,
    int bid, int tid,
    const float* __restrict__ extra32 = nullptr,
    const h16* __restrict__ f2 = nullptr,
    const float* __restrict__ bfp = nullptr,
    float* __restrict__ outf = nullptr)
{
    constexpr int F8 = F / 8;
    int gt = bid * 256 + tid;
    if (gt >= n * F8) return;
    int i = gt / F8;
    int f = gt - i * F8;
    int s = rowptr[i], e = rowptr[i + 1];
    const h16* base = hs + (size_t)f * 8;
    float acc[8];
    ld8h(hs + (size_t)i * F + f * 8, acc);
    int k = s;
    for (; k + 8 <= e; k += 8) {
        int c[8];
        union { uint4 u; h16 h[8]; } a[8];
#pragma unroll
        for (int q = 0; q < 8; ++q) c[q] = (int)col[k + q];
#pragma unroll
        for (int q = 0; q < 8; ++q) a[q].u = *(const uint4*)(base + (size_t)c[q] * F);
#pragma unroll
        for (int j = 0; j < 8; ++j) {
            float t0 = ((float)a[0].h[j] + (float)a[1].h[j]) + ((float)a[2].h[j] + (float)a[3].h[j]);
            float t1 = ((float)a[4].h[j] + (float)a[5].h[j]) + ((float)a[6].h[j] + (float)a[7].h[j]);
            acc[j] += t0 + t1;
        }
    }
    for (; k + 4 <= e; k += 4) {
        int c0 = col[k], c1 = col[k + 1], c2 = col[k + 2], c3 = col[k + 3];
        union { uint4 u; h16 h[8]; } a0, a1, a2, a3;
        a0.u = *(const uint4*)(base + (size_t)c0 * F);
        a1.u = *(const uint4*)(base + (size_t)c1 * F);
        a2.u = *(const uint4*)(base + (size_t)c2 * F);
        a3.u = *(const uint4*)(base + (size_t)c3 * F);
#pragma unroll
        for (int j = 0; j < 8; ++j)
            acc[j] += ((float)a0.h[j] + (float)a1.h[j]) + ((float)a2.h[j] + (float)a3.h[j]);
    }
    for (; k < e; k++) {
        float v[8];
        ld8h(base + (size_t)col[k] * F, v);
#pragma unroll
        for (int j = 0; j < 8; ++j) acc[j] += v[j];
    }
    float dv = dinv[i];
    if constexpr (MODE == 3) {
        float fv[8];
        ld8h(f2 + (size_t)i * F + f * 8, fv);
        float r[8];
#pragma unroll
        for (int j = 0; j < 8; ++j) {
            float t = acc[j] * dv + bias[f * 8 + j] + fv[j] + bfp[f * 8 + j];
            r[j] = 1.f / (1.f + expf(-t));
        }
        float* po = outf + (size_t)i * F + f * 8;
        *(float4*)po       = make_float4(r[0], r[1], r[2], r[3]);
        *(float4*)(po + 4) = make_float4(r[4], r[5], r[6], r[7]);
    } else if constexpr (MODE == 2) {
        const float* pe = extra32 + (size_t)i * F + f * 8;
        float4 e0 = *(const float4*)pe;
        float4 e1 = *(const float4*)(pe + 4);
        float ex[8] = {e0.x, e0.y, e0.z, e0.w, e1.x, e1.y, e1.z, e1.w};
        union { uint4 u; h16 h[8]; } o;
#pragma unroll
        for (int j = 0; j < 8; ++j) o.h[j] = (h16)(acc[j] * dv + bias[f * 8 + j] + ex[j]);
        *(uint4*)(out + (size_t)i * F + f * 8) = o.u;
    } else {
        union { uint4 u; h16 h[8]; } o;
#pragma unroll
        for (int j = 0; j < 8; ++j) o.h[j] = (h16)((acc[j] * dv + bias[f * 8 + j]) * dv);
        *(uint4*)(out + (size_t)i * F + f * 8) = o.u;
    }
}

// plain prescaled hop (label hops 3..9)
__global__ __launch_bounds__(256) void agg40_pre_kernel(
    const h16* __restrict__ hs, const int* __restrict__ rowptr,
    const u16* __restrict__ col, const float* __restrict__ dinv,
    const float* __restrict__ bias, h16* __restrict__ out, int n) {
    agg_body<40, 1>(hs, rowptr, col, dinv, bias, out, n, blockIdx.x, threadIdx.x);
}

// hop 1: label Z0->LA and feature F0->FB, both prescaled
__global__ __launch_bounds__(256) void agg_hop1_kernel(
    const h16* __restrict__ hsA, const float* __restrict__ biasA, h16* __restrict__ outA,
    const h16* __restrict__ hsB, const float* __restrict__ biasB, h16* __restrict__ outB,
    const int* __restrict__ rowptr, const u16* __restrict__ col,
    const float* __restrict__ dinv, int n, int nblkA)
{
    if (blockIdx.x < nblkA)
        agg_body<40, 1>(hsA, rowptr, col, dinv, biasA, outA, n, blockIdx.x, threadIdx.x);
    else
        agg_body<40, 1>(hsB, rowptr, col, dinv, biasB, outB, n, blockIdx.x - nblkA, threadIdx.x);
}

// hop 2: label LA->LB (prescaled) + feature FB->F2 = agg + b2' + DW40
__global__ __launch_bounds__(256) void agg_hop2_kernel(
    const h16* __restrict__ hsA, const float* __restrict__ biasA, h16* __restrict__ outA,
    const h16* __restrict__ hsB, const float* __restrict__ biasB, h16* __restrict__ outB,
    const float* __restrict__ dw40,
    const int* __restrict__ rowptr, const u16* __restrict__ col,
    const float* __restrict__ dinv, int n, int nblkA)
{
    if (blockIdx.x < nblkA)
        agg_body<40, 1>(hsA, rowptr, col, dinv, biasA, outA, n, blockIdx.x, threadIdx.x);
    else
        agg_body<40, 2>(hsB, rowptr, col, dinv, biasB, outB, n, blockIdx.x - nblkA, threadIdx.x, dw40);
}

// hop 10: out = sigmoid(agg(u9)+beta'10 + F2 + bf), f32 out
__global__ __launch_bounds__(256) void agg_final_kernel(
    const h16* __restrict__ hs, const int* __restrict__ rowptr,
    const u16* __restrict__ col, const float* __restrict__ dinv,
    const float* __restrict__ bias, const h16* __restrict__ f2,
    const float* __restrict__ bf, float* __restrict__ outf, int n)
{
    agg_body<40, 3>(hs, rowptr, col, dinv, bias, nullptr, n, blockIdx.x, threadIdx.x,
                    nullptr, f2, bf, outf);
}

extern "C" void kernel_launch(void* const* d_in, const int* in_sizes, int n_in,
                              void* d_out, int out_size, void* d_ws, size_t ws_size,
                              hipStream_t stream) {
    const float* x   = (const float*)d_in[0];
    const float* y   = (const float*)d_in[1];
    const int*   ei  = (const int*)d_in[2];
    const float* dwe = (const float*)d_in[3];
    const float* W1  = (const float*)d_in[4];
    const float* b1  = (const float*)d_in[5];
    const float* W2  = (const float*)d_in[6];
    const float* b2  = (const float*)d_in[7];
    const float* Wl  = (const float*)d_in[8];
    const float* bl  = (const float*)d_in[9];
    const float* Wf  = (const float*)d_in[10];
    const float* bf  = (const float*)d_in[11];
    float* out = (float*)d_out;

    const int n = in_sizes[0] / 128;
    const int E = in_sizes[2] / 2;
    const int* srcp = ei;
    const int* dstp = ei + E;

    char* ws = (char*)d_ws;
    size_t off = 0;
    auto alloc = [&](size_t bytes) -> void* {
        void* p = ws + off;
        off += bytes;
        off = (off + 255) & ~(size_t)255;
        return p;
    };

    int*   cnt     = (int*)alloc((size_t)n * 4);
    float* dinv    = (float*)alloc((size_t)n * 4);
    int*   rowptr  = (int*)alloc((size_t)(n + 1) * 4);
    int*   cursor  = (int*)alloc((size_t)n * 4);
    int*   partial = (int*)alloc(256 * 4);
    u16*   col     = (u16*)alloc((size_t)E * 2);
    h16*   Z0      = (h16*)alloc((size_t)n * 40 * 2);
    h16*   LA      = (h16*)alloc((size_t)n * 40 * 2);
    h16*   LB      = (h16*)alloc((size_t)n * 40 * 2);
    h16*   F0      = (h16*)alloc((size_t)n * 40 * 2);
    h16*   FB      = (h16*)alloc((size_t)n * 40 * 2);
    h16*   F2      = (h16*)alloc((size_t)n * 40 * 2);
    float* DW40    = (float*)alloc((size_t)n * 40 * 4);
    float* CM      = (float*)alloc(1600 * 4);
    float* betas   = (float*)alloc(10 * 40 * 4);
    float* T       = (float*)alloc(96 * 40 * 4);
    float* WF      = (float*)alloc(128 * 40 * 4);
    float* betaf1p = (float*)alloc(40 * 4);
    float* b2p     = (float*)alloc(40 * 4);
    (void)ws_size;

    const int NB      = (n + 1023) / 1024;
    const int gb_gm   = (n + 63) / 64;
    const int gb_a40  = (n * 5 + THREADS - 1) / THREADS;
    const int PART_BLOCKS = 2048;

    // ---- CSR build (XCD-partitioned atomics) + full weight collapse ----
    hipMemsetAsync(cnt, 0, (size_t)n * 4, stream);
    count_part_kernel<<<PART_BLOCKS, THREADS, 0, stream>>>(dstp, cnt, E, n);
    scanp1_pre_kernel<<<NB + 16, THREADS, 0, stream>>>(
        cnt, partial, n, NB, Wl, bl, W2, b1, b2, Wf, CM, betas, T, betaf1p, b2p);
    scanp2_wf_dw_kernel<<<21 + gb_gm, THREADS, 0, stream>>>(
        partial, rowptr, NB, n, W1, T, WF, dwe, Wf + 136 * 40, DW40);
    scan_p3<<<NB, THREADS, 0, stream>>>(cnt, partial, rowptr, cursor, dinv, n);
    scatter_part_kernel<<<PART_BLOCKS, THREADS, 0, stream>>>(srcp, dstp, cursor, col, E, n);

    // ---- input GEMMs (label z0 and feature f0, 40-wide, prescaled) ----
    gemm_kernel<40, 40, float, h16, 1><<<gb_gm, THREADS, 0, stream>>>(y, CM, dinv, Z0, n);
    gemm_kernel<128, 40, float, h16, 1><<<gb_gm, THREADS, 0, stream>>>(x, WF, dinv, F0, n);

    // ---- hop 1: label + feature (both 40-wide, prescaled) ----
    agg_hop1_kernel<<<2 * gb_a40, THREADS, 0, stream>>>(
        Z0, betas + 0, LA, F0, betaf1p, FB, rowptr, col, dinv, n, gb_a40);
    // ---- hop 2: label + feature-final (F2 = agg + b2' + DW40) ----
    agg_hop2_kernel<<<2 * gb_a40, THREADS, 0, stream>>>(
        LA, betas + 40, LB, FB, b2p, F2, DW40, rowptr, col, dinv, n, gb_a40);

    // ---- label hops 3..9 (ping-pong) ----
    const h16* cur = LB;
    for (int m = 3; m <= 9; m++) {
        h16* nxt = (m & 1) ? LA : LB;
        agg40_pre_kernel<<<gb_a40, THREADS, 0, stream>>>(
            cur, rowptr, col, dinv, betas + (size_t)(m - 1) * 40, nxt, n);
        cur = nxt;
    }

    // ---- hop 10 + fuse + sigmoid, writes d_out directly ----
    agg_final_kernel<<<gb_a40, THREADS, 0, stream>>>(
        cur, rowptr, col, dinv, betas + 9 * 40, F2, bf, out, n);
}